// Round 9
// baseline (629.223 us; speedup 1.0000x reference)
//
#include <hip/hip_runtime.h>
#include <hip/hip_bf16.h>

#define N_NODES 50000
#define N_EDGES 300000
#define HID 256
#define AS 264      // LDS act stride in bf16 elems: 264*2=528B = 33*16 -> 16B-aligned rows
#define A0S 40      // A0 stride (ushorts): 80B rows, 16B-aligned

typedef unsigned int uint;
typedef unsigned short ushort;
typedef short bf16x8 __attribute__((ext_vector_type(8)));
typedef unsigned short u16x8 __attribute__((ext_vector_type(8)));
typedef float f32x4 __attribute__((ext_vector_type(4)));

__device__ __forceinline__ float bf2f(ushort u){ union{uint i; float f;} v; v.i=((uint)u)<<16; return v.f; }
__device__ __forceinline__ ushort f2bf(float f){ __hip_bfloat16 h=__float2bfloat16(f); return *reinterpret_cast<ushort*>(&h); }

__device__ __forceinline__ f32x4 mfma16(bf16x8 a, bf16x8 b, f32x4 c){
    return __builtin_amdgcn_mfma_f32_16x16x32_bf16(a, b, c, 0, 0, 0);
}

// wave computes rows 0..63 of act (LDS, row-major stride AS) x cols [n0,n0+64) of WT (bf16 [N][K=256])
__device__ __forceinline__ void wave_gemm(const ushort* act, const ushort* __restrict__ WT,
                                          int n0, int lane, f32x4 acc[4][4])
{
    #pragma unroll
    for (int mi=0;mi<4;mi++)
        #pragma unroll
        for (int ni=0;ni<4;ni++) acc[mi][ni]=(f32x4){0.f,0.f,0.f,0.f};
    const int rA=lane&15, kg=(lane>>4)*8;
    #pragma unroll
    for (int kk=0;kk<8;kk++){
        const int ka=kk*32+kg;
        bf16x8 a[4], b[4];
        #pragma unroll
        for (int mi=0;mi<4;mi++) a[mi]=*(const bf16x8*)&act[(mi*16+rA)*AS+ka];
        #pragma unroll
        for (int ni=0;ni<4;ni++) b[ni]=*(const bf16x8*)&WT[(size_t)((n0+ni*16+rA)*HID+ka)];
        #pragma unroll
        for (int mi=0;mi<4;mi++)
            #pragma unroll
            for (int ni=0;ni<4;ni++)
                acc[mi][ni]=mfma16(a[mi], b[ni], acc[mi][ni]);
    }
}

// scatter C-layout accumulator into act LDS (scalar b16 writes), optional relu
__device__ __forceinline__ void store_c_to_act(ushort* act, const f32x4 acc[4][4],
                                               int colb, int hi, bool relu)
{
    #pragma unroll
    for (int mi=0;mi<4;mi++)
        #pragma unroll
        for (int ni=0;ni<4;ni++)
            #pragma unroll
            for (int r=0;r<4;r++){
                float v=acc[mi][ni][r];
                if (relu) v=fmaxf(v,0.f);
                act[(mi*16+hi*4+r)*AS + colb+ni*16]=f2bf(v);
            }
}

// ---------------- combined weights -> bf16 transposed (+K=32 layer1 weights with bias folded)
__global__ void combine_weights(const float* __restrict__ sW2, const float* __restrict__ sb2,
                                const float* __restrict__ eW2, const float* __restrict__ eb2,
                                const float* __restrict__ gW1, const float* __restrict__ gb1,
                                const float* __restrict__ dW2, const float* __restrict__ gW2,
                                const float* __restrict__ oW1,
                                const float* __restrict__ eW1, const float* __restrict__ eb1,
                                const float* __restrict__ sW1, const float* __restrict__ sb1,
                                const float* __restrict__ dW1, const float* __restrict__ db1,
                                ushort* __restrict__ WT_A, ushort* __restrict__ WT_B, ushort* __restrict__ WT_E,
                                ushort* __restrict__ WT_d, ushort* __restrict__ WT_g, ushort* __restrict__ WT_o,
                                ushort* __restrict__ WT_e1, ushort* __restrict__ WT_s1, ushort* __restrict__ WT_d1,
                                float* __restrict__ bias_A, float* __restrict__ bias_B)
{
    const int j = threadIdx.x;
    const int i = blockIdx.x;   // 0..256 (256 = bias row for m<3)
    const int m = blockIdx.y;   // 0:A 1:B 2:E 3:dW2 4:gW2 5:oW1 6:e1 7:s1 8:d1
    if (m==6){ if (i<32) WT_e1[j*32+i] = f2bf(i<3 ? eW1[i*HID+j] : (i==3 ? eb1[j] : 0.f)); return; }
    if (m==7){ if (i<32) WT_s1[j*32+i] = f2bf(i<10? sW1[i*HID+j] : (i==10? sb1[j] : 0.f)); return; }
    if (m==8){ if (i<32) WT_d1[j*32+i] = f2bf(i<12? dW1[i*HID+j] : (i==12? db1[j] : 0.f)); return; }
    if (m>=3){
        if (i<HID){
            const float* S = (m==3)? dW2 : (m==4)? gW2 : oW1;
            ushort* D      = (m==3)? WT_d : (m==4)? WT_g : WT_o;
            D[j*HID+i]=f2bf(S[i*HID+j]);
        }
        return;
    }
    const float* L  = (m==2)? eW2 : sW2;
    const float* R  = gW1 + (m==0 ? HID*HID : (m==1 ? 2*HID*HID : 0));
    if (i < HID){
        float acc=0.f;
        for (int k=0;k<HID;k++) acc += L[i*HID+k]*R[k*HID+j];
        (m==0?WT_A:(m==1?WT_B:WT_E))[j*HID+i] = f2bf(acc);
    } else if (m==0){
        float acc=gb1[j];
        for (int k=0;k<HID;k++) acc += sb2[k]*gW1[(HID+k)*HID+j];
        for (int k=0;k<HID;k++) acc += eb2[k]*gW1[k*HID+j];
        bias_A[j]=acc;
    } else if (m==1){
        float acc=0.f;
        for (int k=0;k<HID;k++) acc += sb2[k]*gW1[(2*HID+k)*HID+j];
        bias_B[j]=acc;
    }
}

// ---------------- node encoder (all-MFMA): gA/gB (bf16) + h0 (bf16)
__global__ __launch_bounds__(256) void node_encode_mfma(
    const float* __restrict__ sfeat, const float* __restrict__ dfeat,
    const ushort* __restrict__ WT_s1, const ushort* __restrict__ WT_d1,
    const ushort* __restrict__ WT_d, const float* __restrict__ db2,
    const ushort* __restrict__ WT_A, const float* __restrict__ bias_A,
    const ushort* __restrict__ WT_B, const float* __restrict__ bias_B,
    ushort* __restrict__ gA, ushort* __restrict__ gB, ushort* __restrict__ h0)
{
    __shared__ ushort act[64*AS];
    __shared__ ushort A0[64*A0S];
    const int tid=threadIdx.x;
    const int n0blk=blockIdx.x*64;
    const int wv=tid>>6, lane=tid&63, n0=wv*64;
    const int rA=lane&15, kg=(lane>>4)*8, hi=lane>>4;
    const int colb=n0+rA;

    {   // stage A0 = [sfeat(10), 1, 0...]
        const int n=tid>>2, k0=(tid&3)*8;
        const int gn=n0blk+n;
        u16x8 v;
        #pragma unroll
        for (int j=0;j<8;j++){
            const int k=k0+j;
            float f = (gn<N_NODES && k<10)? sfeat[(size_t)gn*10+k] : (k==10? 1.f : 0.f);
            v[j]=f2bf(f);
        }
        *(u16x8*)&A0[n*A0S+k0]=v;
    }
    __syncthreads();
    f32x4 acc[4][4];
    {   // layer1 static: relu(A0 @ WT_s1^T)
        bf16x8 a[4], b[4];
        #pragma unroll
        for (int mi=0;mi<4;mi++) a[mi]=*(const bf16x8*)&A0[(mi*16+rA)*A0S+kg];
        #pragma unroll
        for (int ni=0;ni<4;ni++) b[ni]=*(const bf16x8*)&WT_s1[(size_t)(n0+ni*16+rA)*32+kg];
        #pragma unroll
        for (int mi=0;mi<4;mi++)
            #pragma unroll
            for (int ni=0;ni<4;ni++)
                acc[mi][ni]=mfma16(a[mi], b[ni], (f32x4){0.f,0.f,0.f,0.f});
        store_c_to_act(act, acc, colb, hi, true);
    }
    __syncthreads();
    {   // stage A0 dynamic (A0 free after gemm above)
        const int n=tid>>2, k0=(tid&3)*8;
        const int gn=n0blk+n;
        u16x8 v;
        #pragma unroll
        for (int j=0;j<8;j++){
            const int k=k0+j;
            float f = (gn<N_NODES && k<12)? dfeat[(size_t)gn*12+k] : (k==12? 1.f : 0.f);
            v[j]=f2bf(f);
        }
        *(u16x8*)&A0[n*A0S+k0]=v;
    }
    {   // gA = act @ WT_A^T + bias_A(total)
        wave_gemm(act, WT_A, n0, lane, acc);
        #pragma unroll
        for (int mi=0;mi<4;mi++){
            #pragma unroll
            for (int ni=0;ni<4;ni++){
                const int col=colb+ni*16; const float bA=bias_A[col];
                #pragma unroll
                for (int r=0;r<4;r++){
                    int rr=mi*16+hi*4+r; int gn=n0blk+rr;
                    if (gn<N_NODES) gA[(size_t)gn*HID+col]=f2bf(acc[mi][ni][r]+bA);
                }
            }
        }
    }
    {   // gB
        wave_gemm(act, WT_B, n0, lane, acc);
        #pragma unroll
        for (int mi=0;mi<4;mi++){
            #pragma unroll
            for (int ni=0;ni<4;ni++){
                const int col=colb+ni*16; const float bB=bias_B[col];
                #pragma unroll
                for (int r=0;r<4;r++){
                    int rr=mi*16+hi*4+r; int gn=n0blk+rr;
                    if (gn<N_NODES) gB[(size_t)gn*HID+col]=f2bf(acc[mi][ni][r]+bB);
                }
            }
        }
    }
    __syncthreads();   // all waves done reading act + A0d staged
    {   // layer1 dynamic: relu(A0 @ WT_d1^T)
        bf16x8 a[4], b[4];
        #pragma unroll
        for (int mi=0;mi<4;mi++) a[mi]=*(const bf16x8*)&A0[(mi*16+rA)*A0S+kg];
        #pragma unroll
        for (int ni=0;ni<4;ni++) b[ni]=*(const bf16x8*)&WT_d1[(size_t)(n0+ni*16+rA)*32+kg];
        #pragma unroll
        for (int mi=0;mi<4;mi++)
            #pragma unroll
            for (int ni=0;ni<4;ni++)
                acc[mi][ni]=mfma16(a[mi], b[ni], (f32x4){0.f,0.f,0.f,0.f});
        store_c_to_act(act, acc, colb, hi, true);
    }
    __syncthreads();
    {   // h0 = act @ WT_d^T + db2
        wave_gemm(act, WT_d, n0, lane, acc);
        #pragma unroll
        for (int mi=0;mi<4;mi++){
            #pragma unroll
            for (int ni=0;ni<4;ni++){
                const int col=colb+ni*16; const float bo=db2[col];
                #pragma unroll
                for (int r=0;r<4;r++){
                    int rr=mi*16+hi*4+r; int gn=n0blk+rr;
                    if (gn<N_NODES) h0[(size_t)gn*HID+col]=f2bf(acc[mi][ni][r]+bo);
                }
            }
        }
    }
}

// ---------------- edge phase 1: X = acc1 (raw, bf16) = e1 @ WT_E^T, CSR-slot order, coalesced store
__global__ __launch_bounds__(256) void edge_gemm1(
    const float* __restrict__ eattr, const int* __restrict__ csr_eid,
    const ushort* __restrict__ WT_e1, const ushort* __restrict__ WT_E,
    ushort* __restrict__ X)
{
    __shared__ ushort act[64*AS];
    __shared__ ushort A0[64*A0S];
    __shared__ int ei[64];
    const int tid=threadIdx.x;
    const int bid=blockIdx.x;                       // grid 4688 = 8*586
    const int s0=((bid&7)*586 + (bid>>3))*64;
    const int wv=tid>>6, lane=tid&63, n0=wv*64;
    const int rA=lane&15, kg=(lane>>4)*8, hi=lane>>4;
    const int colb=n0+rA;

    if (tid<64){ int s=s0+tid; ei[tid]=(s<N_EDGES)? csr_eid[s]:0; }
    __syncthreads();
    {   // stage A0 = [eattr(3), 1, 0...]  (4 threads per row)
        const int n=tid>>2, k0=(tid&3)*8;
        const int eid=ei[n];
        u16x8 v;
        #pragma unroll
        for (int j=0;j<8;j++){
            const int k=k0+j;
            float f = (k<3)? eattr[(size_t)eid*3+k] : (k==3? 1.f : 0.f);
            v[j]=f2bf(f);
        }
        *(u16x8*)&A0[n*A0S+k0]=v;
    }
    __syncthreads();
    f32x4 acc[4][4];
    {   // gemm0: e1 = relu(A0 @ WT_e1^T), K=32
        bf16x8 a[4], b[4];
        #pragma unroll
        for (int mi=0;mi<4;mi++) a[mi]=*(const bf16x8*)&A0[(mi*16+rA)*A0S+kg];
        #pragma unroll
        for (int ni=0;ni<4;ni++) b[ni]=*(const bf16x8*)&WT_e1[(size_t)(n0+ni*16+rA)*32+kg];
        #pragma unroll
        for (int mi=0;mi<4;mi++)
            #pragma unroll
            for (int ni=0;ni<4;ni++)
                acc[mi][ni]=mfma16(a[mi], b[ni], (f32x4){0.f,0.f,0.f,0.f});
        store_c_to_act(act, acc, colb, hi, true);
    }
    __syncthreads();
    wave_gemm(act, WT_E, n0, lane, acc);    // gemm1
    __syncthreads();                        // all waves done reading act
    store_c_to_act(act, acc, colb, hi, false);
    __syncthreads();
    // coalesced X store: 64 rows x 32 chunks of 16B
    for (int i=tid;i<64*32;i+=256){
        const int row=i>>5, ch=i&31;
        const int s=s0+row;
        if (s<N_EDGES)
            *(u16x8*)&X[(size_t)s*HID + ch*8] = *(const u16x8*)&act[row*AS + ch*8];
    }
}

// ---------------- edge phase 2: g = relu(X + gA[src] + gB[dst]) @ WT_g2^T + gb2, in-place over X
__global__ __launch_bounds__(256) void edge_gemm2(
    const int* __restrict__ csr_src, const int* __restrict__ csr_dst,
    const ushort* __restrict__ gA, const ushort* __restrict__ gB,
    const ushort* __restrict__ WT_g2, const float* __restrict__ gb2,
    ushort* __restrict__ X)   // in: acc1, out: g  (row-exclusive in-place)
{
    __shared__ ushort act[64*AS];
    const int tid=threadIdx.x;
    const int bid=blockIdx.x;                       // grid 4688 = 8*586
    const int s0=((bid&7)*586 + (bid>>3))*64;
    const int wv=tid>>6, lane=tid&63, n0=wv*64;
    const int rA=lane&15, hi=lane>>4;
    const int colb=n0+rA;

    {   // remap: thread t owns row t>>2, cols (t&3)*64..+64
        const int row=tid>>2, cs=(tid&3)*64;
        const int s=s0+row;
        const int sc=(s<N_EDGES)? s : N_EDGES-1;
        const int si=csr_src[sc], di=csr_dst[sc];
        const ushort* xr=&X [(size_t)sc*HID+cs];
        const ushort* ga=&gA[(size_t)si*HID+cs];
        const ushort* gb=&gB[(size_t)di*HID+cs];
        u16x8 xv[8], av[8], bv[8];
        #pragma unroll
        for (int j=0;j<8;j++) xv[j]=*(const u16x8*)&xr[j*8];
        #pragma unroll
        for (int j=0;j<8;j++) av[j]=*(const u16x8*)&ga[j*8];
        #pragma unroll
        for (int j=0;j<8;j++) bv[j]=*(const u16x8*)&gb[j*8];
        #pragma unroll
        for (int j=0;j<8;j++){
            u16x8 o;
            #pragma unroll
            for (int q=0;q<8;q++)
                o[q]=f2bf(fmaxf(bf2f(xv[j][q])+bf2f(av[j][q])+bf2f(bv[j][q]),0.f));
            *(u16x8*)&act[row*AS+cs+j*8]=o;
        }
    }
    __syncthreads();
    f32x4 acc[4][4];
    wave_gemm(act, WT_g2, n0, lane, acc);
    {   // epilogue: + gb2 -> X[slot] (now g), C-layout direct stores
        #pragma unroll
        for (int mi=0;mi<4;mi++){
            #pragma unroll
            for (int ni=0;ni<4;ni++){
                const int col=colb+ni*16; const float bg=gb2[col];
                #pragma unroll
                for (int r=0;r<4;r++){
                    const int rr=mi*16+hi*4+r;
                    if (s0+rr<N_EDGES)
                        X[(size_t)(s0+rr)*HID+col]=f2bf(acc[mi][ni][r]+bg);
                }
            }
        }
    }
}

// ---------------- CSR build
__global__ void deg_count(const int* __restrict__ eidx, uint* __restrict__ deg){
    int e=blockIdx.x*blockDim.x+threadIdx.x;
    if (e<N_EDGES) atomicAdd(&deg[eidx[N_EDGES+e]],1u);
}

__global__ void scan_kernel(const uint* __restrict__ deg, uint* __restrict__ row_start){
    __shared__ uint wtot[16];
    __shared__ uint woff[17];
    __shared__ uint carry_s;
    const int tid=threadIdx.x, lane=tid&63, wid=tid>>6;
    if (tid==0) carry_s=0;
    __syncthreads();
    for (uint base=0; base<N_NODES; base+=1024){
        uint idx=base+tid;
        uint v=(idx<N_NODES)? deg[idx]:0u;
        uint s=v;
        #pragma unroll
        for (int d=1; d<64; d<<=1){
            uint t=__shfl_up(s,d,64);
            if (lane>=d) s+=t;
        }
        if (lane==63) wtot[wid]=s;
        __syncthreads();
        if (tid==0){ uint r=0; for (int i=0;i<16;i++){ woff[i]=r; r+=wtot[i]; } woff[16]=r; }
        __syncthreads();
        uint excl = carry_s + woff[wid] + s - v;
        if (idx<N_NODES) row_start[idx]=excl;
        __syncthreads();
        if (tid==0) carry_s += woff[16];
        __syncthreads();
    }
}

__global__ void csr_fill(const int* __restrict__ eidx, const uint* __restrict__ row_start,
                         uint* __restrict__ cursor, int* __restrict__ csr_src,
                         int* __restrict__ csr_dst, int* __restrict__ csr_eid){
    int e=blockIdx.x*blockDim.x+threadIdx.x;
    if (e>=N_EDGES) return;
    int d=eidx[N_EDGES+e];
    uint pos=atomicAdd(&cursor[d],1u);
    uint s=row_start[d]+pos;
    csr_src[s]=eidx[e];
    csr_dst[s]=d;
    csr_eid[s]=e;
}

// ---------------- message-passing hop: one wave per node, CSR gather, bf16 h in/out
__global__ __launch_bounds__(256) void hop_kernel(
    const ushort* __restrict__ h_in, ushort* __restrict__ h_out,
    const ushort* __restrict__ g, const int* __restrict__ csr_src,
    const uint* __restrict__ row_start, const uint* __restrict__ deg)
{
    const int gw=(blockIdx.x*blockDim.x+threadIdx.x)>>6;
    if (gw>=N_NODES) return;
    const int c0=(threadIdx.x&63)*4;
    ushort4 hd4=*(const ushort4*)&h_in[(size_t)gw*HID+c0];
    float4 hd; hd.x=bf2f(hd4.x); hd.y=bf2f(hd4.y); hd.z=bf2f(hd4.z); hd.w=bf2f(hd4.w);
    float4 acc=make_float4(0,0,0,0);
    const uint st=row_start[gw], len=deg[gw];
    for (uint u=0;u<len;u++){
        uint s=st+u;
        int sn=csr_src[s];
        ushort4 g4=*(const ushort4*)&g[(size_t)s*HID+c0];
        ushort4 hs4=*(const ushort4*)&h_in[(size_t)sn*HID+c0];
        acc.x += bf2f(g4.x)*(bf2f(hs4.x)-hd.x);
        acc.y += bf2f(g4.y)*(bf2f(hs4.y)-hd.y);
        acc.z += bf2f(g4.z)*(bf2f(hs4.z)-hd.z);
        acc.w += bf2f(g4.w)*(bf2f(hs4.w)-hd.w);
    }
    const float inv=1.f/fmaxf((float)len,1.f);
    ushort4 o; o.x=f2bf(hd.x+acc.x*inv); o.y=f2bf(hd.y+acc.y*inv);
               o.z=f2bf(hd.z+acc.z*inv); o.w=f2bf(hd.w+acc.w*inv);
    *(ushort4*)&h_out[(size_t)gw*HID+c0]=o;
}

// ---------------- decoder (MFMA): out = relu(tanh(h)@oW1+ob1)@oW2+ob2
__global__ __launch_bounds__(256) void decoder_mfma(
    const ushort* __restrict__ h, const ushort* __restrict__ WT_o,
    const float* __restrict__ ob1, const float* __restrict__ oW2, const float* __restrict__ ob2,
    float* __restrict__ out)
{
    __shared__ ushort act[64*AS];
    const int tid=threadIdx.x, n0blk=blockIdx.x*64;
    const int wv=tid>>6, lane=tid&63, n0=wv*64, colb=n0+(lane&15);
    {   // stage tanh(h) -> act (bf16)
        const int row=tid>>2, cc=(tid&3)*64;
        const int gn=n0blk+row;
        #pragma unroll
        for (int k=0;k<64;k+=8){
            u16x8 t;
            if (gn<N_NODES){
                u16x8 v=*(const u16x8*)&h[(size_t)gn*HID+cc+k];
                #pragma unroll
                for (int j=0;j<8;j++) t[j]=f2bf(tanhf(bf2f(v[j])));
            } else {
                #pragma unroll
                for (int j=0;j<8;j++) t[j]=0;
            }
            *(u16x8*)&act[row*AS+cc+k]=t;
        }
    }
    __syncthreads();
    f32x4 acc[4][4];
    wave_gemm(act, WT_o, n0, lane, acc);
    __syncthreads();
    #pragma unroll
    for (int mi=0;mi<4;mi++){
        #pragma unroll
        for (int ni=0;ni<4;ni++){
            const int col=colb+ni*16; const float b1=ob1[col];
            #pragma unroll
            for (int r=0;r<4;r++){
                const int rr=mi*16+(lane>>4)*4+r;
                act[rr*AS+col]=f2bf(fmaxf(acc[mi][ni][r]+b1,0.f));
            }
        }
    }
    __syncthreads();
    if (tid<192){
        const int n=tid/3, o=tid-n*3;
        float a=ob2[o];
        for (int k=0;k<HID;k++) a+=bf2f(act[n*AS+k])*oW2[k*3+o];
        const int gn=n0blk+n;
        if (gn<N_NODES) out[(size_t)gn*3+o]=a;
    }
}

extern "C" void kernel_launch(void* const* d_in, const int* in_sizes, int n_in,
                              void* d_out, int out_size, void* d_ws, size_t ws_size,
                              hipStream_t stream)
{
    (void)in_sizes; (void)n_in; (void)out_size;
    const float* sfeat=(const float*)d_in[0];
    const float* dfeat=(const float*)d_in[1];
    const int*   eidx =(const int*)  d_in[2];
    const float* eattr=(const float*)d_in[3];
    const float* sW1=(const float*)d_in[4];  const float* sb1=(const float*)d_in[5];
    const float* sW2=(const float*)d_in[6];  const float* sb2=(const float*)d_in[7];
    const float* dW1=(const float*)d_in[8];  const float* db1=(const float*)d_in[9];
    const float* dW2=(const float*)d_in[10]; const float* db2=(const float*)d_in[11];
    const float* eW1=(const float*)d_in[12]; const float* eb1=(const float*)d_in[13];
    const float* eW2=(const float*)d_in[14]; const float* eb2=(const float*)d_in[15];
    const float* gW1=(const float*)d_in[16]; const float* gb1=(const float*)d_in[17];
    const float* gW2=(const float*)d_in[18]; const float* gb2=(const float*)d_in[19];
    const float* oW1=(const float*)d_in[20]; const float* ob1=(const float*)d_in[21];
    const float* oW2=(const float*)d_in[22]; const float* ob2=(const float*)d_in[23];
    float* out=(float*)d_out;

    char* p=(char*)d_ws;
    size_t used=0;
    auto alloc=[&](size_t bytes)->char*{
        char* r=p+used; used += (bytes+255)&~(size_t)255; return r;
    };
    ushort* WT_A=(ushort*)alloc(HID*HID*2);
    ushort* WT_B=(ushort*)alloc(HID*HID*2);
    ushort* WT_E=(ushort*)alloc(HID*HID*2);
    ushort* WT_d=(ushort*)alloc(HID*HID*2);
    ushort* WT_g=(ushort*)alloc(HID*HID*2);
    ushort* WT_o=(ushort*)alloc(HID*HID*2);
    ushort* WT_e1=(ushort*)alloc(HID*32*2);
    ushort* WT_s1=(ushort*)alloc(HID*32*2);
    ushort* WT_d1=(ushort*)alloc(HID*32*2);
    float* bias_A=(float*)alloc(HID*4);
    float* bias_B=(float*)alloc(HID*4);
    ushort* gA=(ushort*)alloc((size_t)N_NODES*HID*2);
    ushort* gB=(ushort*)alloc((size_t)N_NODES*HID*2);
    ushort* g =(ushort*)alloc((size_t)N_EDGES*HID*2);   // doubles as X (phase-1 output)
    ushort* h0=(ushort*)alloc((size_t)N_NODES*HID*2);
    uint* deg      =(uint*)alloc(N_NODES*4);
    uint* row_start=(uint*)alloc(N_NODES*4);
    uint* cursor   =(uint*)alloc(N_NODES*4);
    int* csr_src=(int*)alloc(N_EDGES*4);
    int* csr_dst=(int*)alloc(N_EDGES*4);
    int* csr_eid=(int*)alloc(N_EDGES*4);
    ushort* h1=gA;   // alias: gA/gB dead after edge_gemm2

    if (used > ws_size) return;  // clean fail if ws too small

    hipMemsetAsync(deg, 0, N_NODES*4, stream);
    hipMemsetAsync(cursor, 0, N_NODES*4, stream);

    combine_weights<<<dim3(HID+1,9),256,0,stream>>>(sW2,sb2,eW2,eb2,gW1,gb1,dW2,gW2,oW1,eW1,eb1,sW1,sb1,dW1,db1,
                                                    WT_A,WT_B,WT_E,WT_d,WT_g,WT_o,WT_e1,WT_s1,WT_d1,bias_A,bias_B);
    node_encode_mfma<<<(N_NODES+63)/64,256,0,stream>>>(sfeat,dfeat,WT_s1,WT_d1,WT_d,db2,WT_A,bias_A,WT_B,bias_B,gA,gB,h0);
    deg_count<<<(N_EDGES+255)/256,256,0,stream>>>(eidx,deg);
    scan_kernel<<<1,1024,0,stream>>>(deg,row_start);
    csr_fill<<<(N_EDGES+255)/256,256,0,stream>>>(eidx,row_start,cursor,csr_src,csr_dst,csr_eid);
    edge_gemm1<<<(N_EDGES+63)/64,256,0,stream>>>(eattr,csr_eid,WT_e1,WT_E,g);
    edge_gemm2<<<(N_EDGES+63)/64,256,0,stream>>>(csr_src,csr_dst,gA,gB,WT_g,gb2,g);
    hop_kernel<<<N_NODES/4,256,0,stream>>>(h0,h1,g,csr_src,row_start,deg);
    hop_kernel<<<N_NODES/4,256,0,stream>>>(h1,h0,g,csr_src,row_start,deg);
    decoder_mfma<<<(N_NODES+63)/64,256,0,stream>>>(h0,WT_o,ob1,oW2,ob2,out);
}

// Round 13
// 562.847 us; speedup vs baseline: 1.1179x; 1.1179x over previous
//
#include <hip/hip_runtime.h>
#include <hip/hip_bf16.h>

#define N_NODES 50000
#define N_EDGES 300000
#define HID 256
#define AS 264      // LDS act stride in bf16 elems: 264*2=528B = 33*16 -> 16B-aligned rows
#define A0S 40      // A0 stride (ushorts): 80B rows, 16B-aligned

typedef unsigned int uint;
typedef unsigned short ushort;
typedef short bf16x8 __attribute__((ext_vector_type(8)));
typedef unsigned short u16x8 __attribute__((ext_vector_type(8)));
typedef float f32x4 __attribute__((ext_vector_type(4)));

__device__ __forceinline__ float bf2f(ushort u){ union{uint i; float f;} v; v.i=((uint)u)<<16; return v.f; }
__device__ __forceinline__ ushort f2bf(float f){ __hip_bfloat16 h=__float2bfloat16(f); return *reinterpret_cast<ushort*>(&h); }

__device__ __forceinline__ f32x4 mfma16(bf16x8 a, bf16x8 b, f32x4 c){
    return __builtin_amdgcn_mfma_f32_16x16x32_bf16(a, b, c, 0, 0, 0);
}

// wave computes rows 0..63 of act (LDS, row-major stride AS) x cols [n0,n0+64) of WT (bf16 [N][K=256])
__device__ __forceinline__ void wave_gemm(const ushort* act, const ushort* __restrict__ WT,
                                          int n0, int lane, f32x4 acc[4][4])
{
    #pragma unroll
    for (int mi=0;mi<4;mi++)
        #pragma unroll
        for (int ni=0;ni<4;ni++) acc[mi][ni]=(f32x4){0.f,0.f,0.f,0.f};
    const int rA=lane&15, kg=(lane>>4)*8;
    #pragma unroll
    for (int kk=0;kk<8;kk++){
        const int ka=kk*32+kg;
        bf16x8 a[4], b[4];
        #pragma unroll
        for (int mi=0;mi<4;mi++) a[mi]=*(const bf16x8*)&act[(mi*16+rA)*AS+ka];
        #pragma unroll
        for (int ni=0;ni<4;ni++) b[ni]=*(const bf16x8*)&WT[(size_t)((n0+ni*16+rA)*HID+ka)];
        #pragma unroll
        for (int mi=0;mi<4;mi++)
            #pragma unroll
            for (int ni=0;ni<4;ni++)
                acc[mi][ni]=mfma16(a[mi], b[ni], acc[mi][ni]);
    }
}

// scatter C-layout accumulator into act LDS (scalar b16 writes), optional relu
__device__ __forceinline__ void store_c_to_act(ushort* act, const f32x4 acc[4][4],
                                               int colb, int hi, bool relu)
{
    #pragma unroll
    for (int mi=0;mi<4;mi++)
        #pragma unroll
        for (int ni=0;ni<4;ni++)
            #pragma unroll
            for (int r=0;r<4;r++){
                float v=acc[mi][ni][r];
                if (relu) v=fmaxf(v,0.f);
                act[(mi*16+hi*4+r)*AS + colb+ni*16]=f2bf(v);
            }
}

// ---------------- combined weights -> bf16 transposed (+K=32 layer1 weights with bias folded)
__global__ void combine_weights(const float* __restrict__ sW2, const float* __restrict__ sb2,
                                const float* __restrict__ eW2, const float* __restrict__ eb2,
                                const float* __restrict__ gW1, const float* __restrict__ gb1,
                                const float* __restrict__ dW2, const float* __restrict__ gW2,
                                const float* __restrict__ oW1,
                                const float* __restrict__ eW1, const float* __restrict__ eb1,
                                const float* __restrict__ sW1, const float* __restrict__ sb1,
                                const float* __restrict__ dW1, const float* __restrict__ db1,
                                ushort* __restrict__ WT_A, ushort* __restrict__ WT_B, ushort* __restrict__ WT_E,
                                ushort* __restrict__ WT_d, ushort* __restrict__ WT_g, ushort* __restrict__ WT_o,
                                ushort* __restrict__ WT_e1, ushort* __restrict__ WT_s1, ushort* __restrict__ WT_d1,
                                float* __restrict__ bias_A, float* __restrict__ bias_B)
{
    const int j = threadIdx.x;
    const int i = blockIdx.x;   // 0..256 (256 = bias row for m<3)
    const int m = blockIdx.y;   // 0:A 1:B 2:E 3:dW2 4:gW2 5:oW1 6:e1 7:s1 8:d1
    if (m==6){ if (i<32) WT_e1[j*32+i] = f2bf(i<3 ? eW1[i*HID+j] : (i==3 ? eb1[j] : 0.f)); return; }
    if (m==7){ if (i<32) WT_s1[j*32+i] = f2bf(i<10? sW1[i*HID+j] : (i==10? sb1[j] : 0.f)); return; }
    if (m==8){ if (i<32) WT_d1[j*32+i] = f2bf(i<12? dW1[i*HID+j] : (i==12? db1[j] : 0.f)); return; }
    if (m>=3){
        if (i<HID){
            const float* S = (m==3)? dW2 : (m==4)? gW2 : oW1;
            ushort* D      = (m==3)? WT_d : (m==4)? WT_g : WT_o;
            D[j*HID+i]=f2bf(S[i*HID+j]);
        }
        return;
    }
    const float* L  = (m==2)? eW2 : sW2;
    const float* R  = gW1 + (m==0 ? HID*HID : (m==1 ? 2*HID*HID : 0));
    if (i < HID){
        float acc=0.f;
        for (int k=0;k<HID;k++) acc += L[i*HID+k]*R[k*HID+j];
        (m==0?WT_A:(m==1?WT_B:WT_E))[j*HID+i] = f2bf(acc);
    } else if (m==0){
        float acc=gb1[j];
        for (int k=0;k<HID;k++) acc += sb2[k]*gW1[(HID+k)*HID+j];
        for (int k=0;k<HID;k++) acc += eb2[k]*gW1[k*HID+j];
        bias_A[j]=acc;
    } else if (m==1){
        float acc=0.f;
        for (int k=0;k<HID;k++) acc += sb2[k]*gW1[(2*HID+k)*HID+j];
        bias_B[j]=acc;
    }
}

// ---------------- node encoder (all-MFMA): gA/gB (bf16) + h0 (bf16)
__global__ __launch_bounds__(256) void node_encode_mfma(
    const float* __restrict__ sfeat, const float* __restrict__ dfeat,
    const ushort* __restrict__ WT_s1, const ushort* __restrict__ WT_d1,
    const ushort* __restrict__ WT_d, const float* __restrict__ db2,
    const ushort* __restrict__ WT_A, const float* __restrict__ bias_A,
    const ushort* __restrict__ WT_B, const float* __restrict__ bias_B,
    ushort* __restrict__ gA, ushort* __restrict__ gB, ushort* __restrict__ h0)
{
    __shared__ ushort act[64*AS];
    __shared__ ushort A0[64*A0S];
    const int tid=threadIdx.x;
    const int n0blk=blockIdx.x*64;
    const int wv=tid>>6, lane=tid&63, n0=wv*64;
    const int rA=lane&15, kg=(lane>>4)*8, hi=lane>>4;
    const int colb=n0+rA;

    {   // stage A0 = [sfeat(10), 1, 0...]
        const int n=tid>>2, k0=(tid&3)*8;
        const int gn=n0blk+n;
        u16x8 v;
        #pragma unroll
        for (int j=0;j<8;j++){
            const int k=k0+j;
            float f = (gn<N_NODES && k<10)? sfeat[(size_t)gn*10+k] : (k==10? 1.f : 0.f);
            v[j]=f2bf(f);
        }
        *(u16x8*)&A0[n*A0S+k0]=v;
    }
    __syncthreads();
    f32x4 acc[4][4];
    {   // layer1 static: relu(A0 @ WT_s1^T)
        bf16x8 a[4], b[4];
        #pragma unroll
        for (int mi=0;mi<4;mi++) a[mi]=*(const bf16x8*)&A0[(mi*16+rA)*A0S+kg];
        #pragma unroll
        for (int ni=0;ni<4;ni++) b[ni]=*(const bf16x8*)&WT_s1[(size_t)(n0+ni*16+rA)*32+kg];
        #pragma unroll
        for (int mi=0;mi<4;mi++)
            #pragma unroll
            for (int ni=0;ni<4;ni++)
                acc[mi][ni]=mfma16(a[mi], b[ni], (f32x4){0.f,0.f,0.f,0.f});
        store_c_to_act(act, acc, colb, hi, true);
    }
    __syncthreads();
    {   // stage A0 dynamic (A0 free after gemm above)
        const int n=tid>>2, k0=(tid&3)*8;
        const int gn=n0blk+n;
        u16x8 v;
        #pragma unroll
        for (int j=0;j<8;j++){
            const int k=k0+j;
            float f = (gn<N_NODES && k<12)? dfeat[(size_t)gn*12+k] : (k==12? 1.f : 0.f);
            v[j]=f2bf(f);
        }
        *(u16x8*)&A0[n*A0S+k0]=v;
    }
    {   // gA = act @ WT_A^T + bias_A(total)
        wave_gemm(act, WT_A, n0, lane, acc);
        #pragma unroll
        for (int mi=0;mi<4;mi++){
            #pragma unroll
            for (int ni=0;ni<4;ni++){
                const int col=colb+ni*16; const float bA=bias_A[col];
                #pragma unroll
                for (int r=0;r<4;r++){
                    int rr=mi*16+hi*4+r; int gn=n0blk+rr;
                    if (gn<N_NODES) gA[(size_t)gn*HID+col]=f2bf(acc[mi][ni][r]+bA);
                }
            }
        }
    }
    {   // gB
        wave_gemm(act, WT_B, n0, lane, acc);
        #pragma unroll
        for (int mi=0;mi<4;mi++){
            #pragma unroll
            for (int ni=0;ni<4;ni++){
                const int col=colb+ni*16; const float bB=bias_B[col];
                #pragma unroll
                for (int r=0;r<4;r++){
                    int rr=mi*16+hi*4+r; int gn=n0blk+rr;
                    if (gn<N_NODES) gB[(size_t)gn*HID+col]=f2bf(acc[mi][ni][r]+bB);
                }
            }
        }
    }
    __syncthreads();   // all waves done reading act + A0d staged
    {   // layer1 dynamic: relu(A0 @ WT_d1^T)
        bf16x8 a[4], b[4];
        #pragma unroll
        for (int mi=0;mi<4;mi++) a[mi]=*(const bf16x8*)&A0[(mi*16+rA)*A0S+kg];
        #pragma unroll
        for (int ni=0;ni<4;ni++) b[ni]=*(const bf16x8*)&WT_d1[(size_t)(n0+ni*16+rA)*32+kg];
        #pragma unroll
        for (int mi=0;mi<4;mi++)
            #pragma unroll
            for (int ni=0;ni<4;ni++)
                acc[mi][ni]=mfma16(a[mi], b[ni], (f32x4){0.f,0.f,0.f,0.f});
        store_c_to_act(act, acc, colb, hi, true);
    }
    __syncthreads();
    {   // h0 = act @ WT_d^T + db2
        wave_gemm(act, WT_d, n0, lane, acc);
        #pragma unroll
        for (int mi=0;mi<4;mi++){
            #pragma unroll
            for (int ni=0;ni<4;ni++){
                const int col=colb+ni*16; const float bo=db2[col];
                #pragma unroll
                for (int r=0;r<4;r++){
                    int rr=mi*16+hi*4+r; int gn=n0blk+rr;
                    if (gn<N_NODES) h0[(size_t)gn*HID+col]=f2bf(acc[mi][ni][r]+bo);
                }
            }
        }
    }
}

// ---------------- edge encoder: 128-edge tile, 8 waves (2M x 4N), all-MFMA, CSR-slot order
// (exact round-8 structure — last known-green; prefetch experiments reverted)
__global__ __launch_bounds__(512) void edge_encode_mfma(
    const float* __restrict__ eattr, const int* __restrict__ eidx,
    const int* __restrict__ csr_src, const int* __restrict__ csr_eid,
    const ushort* __restrict__ WT_e1,
    const ushort* __restrict__ WT_E,
    const ushort* __restrict__ WT_g2, const float* __restrict__ gb2,
    const ushort* __restrict__ gA, const ushort* __restrict__ gB,
    ushort* __restrict__ g_out)
{
    __shared__ ushort act[128*AS];    // 67.6 KB
    __shared__ ushort A0[128*A0S];    // 10.25 KB
    __shared__ int si[128], di[128], ei[128];
    const int tid=threadIdx.x;
    // XCD-aware swizzle: grid = 2344 = 8*293 exactly -> bijective
    const int bid=blockIdx.x;
    const int s0=((bid&7)*293 + (bid>>3))*128;
    const int wv=tid>>6, lane=tid&63;
    const int wm=wv>>2, wn=wv&3;          // 2M x 4N wave grid
    const int m0=wm*64, n0=wn*64;
    const int rA=lane&15, kg=(lane>>4)*8, hi=lane>>4;
    const int colb=n0+rA;

    if (tid<128){
        int s=s0+tid; bool v=s<N_EDGES;
        int eid=v? csr_eid[s]:0;
        si[tid]=v? csr_src[s]:0;
        di[tid]=v? eidx[N_EDGES+eid]:0;
        ei[tid]=eid;
    }
    __syncthreads();
    {   // stage A0 = [eattr(3), 1, 0...]  (4 threads per row)
        const int n=tid>>2, k0=(tid&3)*8;
        const int eid=ei[n];
        u16x8 v;
        #pragma unroll
        for (int j=0;j<8;j++){
            const int k=k0+j;
            float f = (k<3)? eattr[(size_t)eid*3+k] : (k==3? 1.f : 0.f);
            v[j]=f2bf(f);
        }
        *(u16x8*)&A0[n*A0S+k0]=v;
    }
    __syncthreads();
    f32x4 acc[4][4];
    {   // gemm0: e1 = relu(A0 @ WT_e1^T), K=32, rows m0..m0+63
        bf16x8 a[4], b[4];
        #pragma unroll
        for (int mi=0;mi<4;mi++) a[mi]=*(const bf16x8*)&A0[(m0+mi*16+rA)*A0S+kg];
        #pragma unroll
        for (int ni=0;ni<4;ni++) b[ni]=*(const bf16x8*)&WT_e1[(size_t)(n0+ni*16+rA)*32+kg];
        #pragma unroll
        for (int mi=0;mi<4;mi++)
            #pragma unroll
            for (int ni=0;ni<4;ni++)
                acc[mi][ni]=mfma16(a[mi], b[ni], (f32x4){0.f,0.f,0.f,0.f});
        store_c_to_act(act + m0*AS, acc, colb, hi, true);
    }
    __syncthreads();
    wave_gemm(act + m0*AS, WT_E, n0, lane, acc);   // gemm1 on own 64-row group
    __syncthreads();                               // all waves done reading act
    store_c_to_act(act + m0*AS, acc, colb, hi, false);   // raw acc1 into own 64x64 patch
    {   // fused remap of own patch (intra-wave dep only):
        // act[m0+lane][n0..n0+64) = relu(acc1 + gA[src] + gB[dst])
        const int row=m0+lane;
        const ushort* garow=&gA[(size_t)si[row]*HID + n0];
        const ushort* gbrow=&gB[(size_t)di[row]*HID + n0];
        ushort* arow=&act[row*AS + n0];
        #pragma unroll
        for (int j=0;j<8;j++){
            const int jb=((j+lane)&7)*8;
            u16x8 av=*(u16x8*)&arow[jb];
            u16x8 ga=*(const u16x8*)&garow[jb];
            u16x8 gb=*(const u16x8*)&gbrow[jb];
            u16x8 o;
            #pragma unroll
            for (int q=0;q<8;q++)
                o[q]=f2bf(fmaxf(bf2f(av[q])+bf2f(ga[q])+bf2f(gb[q]),0.f));
            *(u16x8*)&arow[jb]=o;
        }
    }
    __syncthreads();
    wave_gemm(act + m0*AS, WT_g2, n0, lane, acc);  // gemm2
    {   // epilogue: + gb2 -> g_out[slot] (C-layout direct stores)
        #pragma unroll
        for (int mi=0;mi<4;mi++){
            #pragma unroll
            for (int ni=0;ni<4;ni++){
                const int col=colb+ni*16; const float bg=gb2[col];
                #pragma unroll
                for (int r=0;r<4;r++){
                    const int rr=m0+mi*16+hi*4+r;
                    if (s0+rr<N_EDGES)
                        g_out[(size_t)(s0+rr)*HID+col]=f2bf(acc[mi][ni][r]+bg);
                }
            }
        }
    }
}

// ---------------- CSR build
__global__ void deg_count(const int* __restrict__ eidx, uint* __restrict__ deg){
    int e=blockIdx.x*blockDim.x+threadIdx.x;
    if (e<N_EDGES) atomicAdd(&deg[eidx[N_EDGES+e]],1u);
}

__global__ void scan_kernel(const uint* __restrict__ deg, uint* __restrict__ row_start){
    __shared__ uint wtot[16];
    __shared__ uint woff[17];
    __shared__ uint carry_s;
    const int tid=threadIdx.x, lane=tid&63, wid=tid>>6;
    if (tid==0) carry_s=0;
    __syncthreads();
    for (uint base=0; base<N_NODES; base+=1024){
        uint idx=base+tid;
        uint v=(idx<N_NODES)? deg[idx]:0u;
        uint s=v;
        #pragma unroll
        for (int d=1; d<64; d<<=1){
            uint t=__shfl_up(s,d,64);
            if (lane>=d) s+=t;
        }
        if (lane==63) wtot[wid]=s;
        __syncthreads();
        if (tid==0){ uint r=0; for (int i=0;i<16;i++){ woff[i]=r; r+=wtot[i]; } woff[16]=r; }
        __syncthreads();
        uint excl = carry_s + woff[wid] + s - v;
        if (idx<N_NODES) row_start[idx]=excl;
        __syncthreads();
        if (tid==0) carry_s += woff[16];
        __syncthreads();
    }
}

__global__ void csr_fill(const int* __restrict__ eidx, const uint* __restrict__ row_start,
                         uint* __restrict__ cursor, int* __restrict__ csr_src, int* __restrict__ csr_eid){
    int e=blockIdx.x*blockDim.x+threadIdx.x;
    if (e>=N_EDGES) return;
    int d=eidx[N_EDGES+e];
    uint pos=atomicAdd(&cursor[d],1u);
    uint s=row_start[d]+pos;
    csr_src[s]=eidx[e];
    csr_eid[s]=e;
}

// ---------------- message-passing hop: one wave per node, CSR gather, bf16 h in/out
// 2x-unrolled neighbor loop (independent chains); TANH=true fuses the gnn activation on output
template<bool TANH>
__global__ __launch_bounds__(256) void hop_kernel(
    const ushort* __restrict__ h_in, ushort* __restrict__ h_out,
    const ushort* __restrict__ g, const int* __restrict__ csr_src,
    const uint* __restrict__ row_start, const uint* __restrict__ deg)
{
    const int gw=(blockIdx.x*blockDim.x+threadIdx.x)>>6;
    if (gw>=N_NODES) return;
    const int c0=(threadIdx.x&63)*4;
    ushort4 hd4=*(const ushort4*)&h_in[(size_t)gw*HID+c0];
    float4 hd; hd.x=bf2f(hd4.x); hd.y=bf2f(hd4.y); hd.z=bf2f(hd4.z); hd.w=bf2f(hd4.w);
    float4 acc0=make_float4(0,0,0,0), acc1=make_float4(0,0,0,0);
    const uint st=row_start[gw], len=deg[gw];
    uint u=0;
    for (; u+2<=len; u+=2){
        uint sa=st+u, sb=st+u+1;
        int na=csr_src[sa], nb=csr_src[sb];
        ushort4 ga=*(const ushort4*)&g[(size_t)sa*HID+c0];
        ushort4 gb=*(const ushort4*)&g[(size_t)sb*HID+c0];
        ushort4 ha=*(const ushort4*)&h_in[(size_t)na*HID+c0];
        ushort4 hb=*(const ushort4*)&h_in[(size_t)nb*HID+c0];
        acc0.x += bf2f(ga.x)*(bf2f(ha.x)-hd.x);
        acc0.y += bf2f(ga.y)*(bf2f(ha.y)-hd.y);
        acc0.z += bf2f(ga.z)*(bf2f(ha.z)-hd.z);
        acc0.w += bf2f(ga.w)*(bf2f(ha.w)-hd.w);
        acc1.x += bf2f(gb.x)*(bf2f(hb.x)-hd.x);
        acc1.y += bf2f(gb.y)*(bf2f(hb.y)-hd.y);
        acc1.z += bf2f(gb.z)*(bf2f(hb.z)-hd.z);
        acc1.w += bf2f(gb.w)*(bf2f(hb.w)-hd.w);
    }
    if (u<len){
        uint sa=st+u;
        int na=csr_src[sa];
        ushort4 ga=*(const ushort4*)&g[(size_t)sa*HID+c0];
        ushort4 ha=*(const ushort4*)&h_in[(size_t)na*HID+c0];
        acc0.x += bf2f(ga.x)*(bf2f(ha.x)-hd.x);
        acc0.y += bf2f(ga.y)*(bf2f(ha.y)-hd.y);
        acc0.z += bf2f(ga.z)*(bf2f(ha.z)-hd.z);
        acc0.w += bf2f(ga.w)*(bf2f(ha.w)-hd.w);
    }
    const float inv=1.f/fmaxf((float)len,1.f);
    float vx=hd.x+(acc0.x+acc1.x)*inv, vy=hd.y+(acc0.y+acc1.y)*inv;
    float vz=hd.z+(acc0.z+acc1.z)*inv, vw=hd.w+(acc0.w+acc1.w)*inv;
    if (TANH){ vx=tanhf(vx); vy=tanhf(vy); vz=tanhf(vz); vw=tanhf(vw); }
    ushort4 o; o.x=f2bf(vx); o.y=f2bf(vy); o.z=f2bf(vz); o.w=f2bf(vw);
    *(ushort4*)&h_out[(size_t)gw*HID+c0]=o;
}

// ---------------- decoder (MFMA): out = relu(x@oW1+ob1)@oW2+ob2   (x = tanh(h), pre-applied by hop2)
__global__ __launch_bounds__(256) void decoder_mfma(
    const ushort* __restrict__ x, const ushort* __restrict__ WT_o,
    const float* __restrict__ ob1, const float* __restrict__ oW2, const float* __restrict__ ob2,
    float* __restrict__ out)
{
    __shared__ ushort act[64*AS];
    const int tid=threadIdx.x, n0blk=blockIdx.x*64;
    const int wv=tid>>6, lane=tid&63, n0=wv*64, colb=n0+(lane&15);
    {   // stage x -> act (pure copy; tanh already applied)
        const int row=tid>>2, cc=(tid&3)*64;
        const int gn=n0blk+row;
        #pragma unroll
        for (int k=0;k<64;k+=8){
            u16x8 t;
            #pragma unroll
            for (int j=0;j<8;j++) t[j]=0;
            if (gn<N_NODES) t=*(const u16x8*)&x[(size_t)gn*HID+cc+k];
            *(u16x8*)&act[row*AS+cc+k]=t;
        }
    }
    __syncthreads();
    f32x4 acc[4][4];
    wave_gemm(act, WT_o, n0, lane, acc);
    __syncthreads();
    #pragma unroll
    for (int mi=0;mi<4;mi++){
        #pragma unroll
        for (int ni=0;ni<4;ni++){
            const int col=colb+ni*16; const float b1=ob1[col];
            #pragma unroll
            for (int r=0;r<4;r++){
                const int rr=mi*16+(lane>>4)*4+r;
                act[rr*AS+col]=f2bf(fmaxf(acc[mi][ni][r]+b1,0.f));
            }
        }
    }
    __syncthreads();
    if (tid<192){
        const int n=tid/3, o=tid-n*3;
        float a=ob2[o];
        for (int k=0;k<HID;k++) a+=bf2f(act[n*AS+k])*oW2[k*3+o];
        const int gn=n0blk+n;
        if (gn<N_NODES) out[(size_t)gn*3+o]=a;
    }
}

extern "C" void kernel_launch(void* const* d_in, const int* in_sizes, int n_in,
                              void* d_out, int out_size, void* d_ws, size_t ws_size,
                              hipStream_t stream)
{
    (void)in_sizes; (void)n_in; (void)out_size;
    const float* sfeat=(const float*)d_in[0];
    const float* dfeat=(const float*)d_in[1];
    const int*   eidx =(const int*)  d_in[2];
    const float* eattr=(const float*)d_in[3];
    const float* sW1=(const float*)d_in[4];  const float* sb1=(const float*)d_in[5];
    const float* sW2=(const float*)d_in[6];  const float* sb2=(const float*)d_in[7];
    const float* dW1=(const float*)d_in[8];  const float* db1=(const float*)d_in[9];
    const float* dW2=(const float*)d_in[10]; const float* db2=(const float*)d_in[11];
    const float* eW1=(const float*)d_in[12]; const float* eb1=(const float*)d_in[13];
    const float* eW2=(const float*)d_in[14]; const float* eb2=(const float*)d_in[15];
    const float* gW1=(const float*)d_in[16]; const float* gb1=(const float*)d_in[17];
    const float* gW2=(const float*)d_in[18]; const float* gb2=(const float*)d_in[19];
    const float* oW1=(const float*)d_in[20]; const float* ob1=(const float*)d_in[21];
    const float* oW2=(const float*)d_in[22]; const float* ob2=(const float*)d_in[23];
    float* out=(float*)d_out;

    char* p=(char*)d_ws;
    size_t used=0;
    auto alloc=[&](size_t bytes)->char*{
        char* r=p+used; used += (bytes+255)&~(size_t)255; return r;
    };
    ushort* WT_A=(ushort*)alloc(HID*HID*2);
    ushort* WT_B=(ushort*)alloc(HID*HID*2);
    ushort* WT_E=(ushort*)alloc(HID*HID*2);
    ushort* WT_d=(ushort*)alloc(HID*HID*2);
    ushort* WT_g=(ushort*)alloc(HID*HID*2);
    ushort* WT_o=(ushort*)alloc(HID*HID*2);
    ushort* WT_e1=(ushort*)alloc(HID*32*2);
    ushort* WT_s1=(ushort*)alloc(HID*32*2);
    ushort* WT_d1=(ushort*)alloc(HID*32*2);
    float* bias_A=(float*)alloc(HID*4);
    float* bias_B=(float*)alloc(HID*4);
    ushort* gA=(ushort*)alloc((size_t)N_NODES*HID*2);
    ushort* gB=(ushort*)alloc((size_t)N_NODES*HID*2);
    ushort* g =(ushort*)alloc((size_t)N_EDGES*HID*2);
    ushort* h0=(ushort*)alloc((size_t)N_NODES*HID*2);
    uint* deg      =(uint*)alloc(N_NODES*4);
    uint* row_start=(uint*)alloc(N_NODES*4);
    uint* cursor   =(uint*)alloc(N_NODES*4);
    int* csr_src=(int*)alloc(N_EDGES*4);
    int* csr_eid=(int*)alloc(N_EDGES*4);
    ushort* h1=gA;   // alias: gA/gB dead after edge_encode

    if (used > ws_size) return;  // clean fail if ws too small

    hipMemsetAsync(deg, 0, N_NODES*4, stream);
    hipMemsetAsync(cursor, 0, N_NODES*4, stream);

    combine_weights<<<dim3(HID+1,9),256,0,stream>>>(sW2,sb2,eW2,eb2,gW1,gb1,dW2,gW2,oW1,eW1,eb1,sW1,sb1,dW1,db1,
                                                    WT_A,WT_B,WT_E,WT_d,WT_g,WT_o,WT_e1,WT_s1,WT_d1,bias_A,bias_B);
    node_encode_mfma<<<(N_NODES+63)/64,256,0,stream>>>(sfeat,dfeat,WT_s1,WT_d1,WT_d,db2,WT_A,bias_A,WT_B,bias_B,gA,gB,h0);
    deg_count<<<(N_EDGES+255)/256,256,0,stream>>>(eidx,deg);
    scan_kernel<<<1,1024,0,stream>>>(deg,row_start);
    csr_fill<<<(N_EDGES+255)/256,256,0,stream>>>(eidx,row_start,cursor,csr_src,csr_eid);
    edge_encode_mfma<<<(N_EDGES+127)/128,512,0,stream>>>(eattr,eidx,csr_src,csr_eid,WT_e1,WT_E,WT_g,gb2,gA,gB,g);
    hop_kernel<false><<<N_NODES/4,256,0,stream>>>(h0,h1,g,csr_src,row_start,deg);
    hop_kernel<true ><<<N_NODES/4,256,0,stream>>>(h1,h0,g,csr_src,row_start,deg);
    decoder_mfma<<<(N_NODES+63)/64,256,0,stream>>>(h0,WT_o,ob1,oW2,ob2,out);
}

// Round 14
// 532.374 us; speedup vs baseline: 1.1819x; 1.0572x over previous
//
#include <hip/hip_runtime.h>
#include <hip/hip_bf16.h>

#define N_NODES 50000
#define N_EDGES 300000
#define HID 256
#define AS 264      // LDS act stride in bf16 elems: 264*2=528B = 33*16 -> 16B-aligned rows
#define A0S 40      // A0 stride (ushorts): 80B rows, 16B-aligned

typedef unsigned int uint;
typedef unsigned short ushort;
typedef short bf16x8 __attribute__((ext_vector_type(8)));
typedef unsigned short u16x8 __attribute__((ext_vector_type(8)));
typedef float f32x4 __attribute__((ext_vector_type(4)));

__device__ __forceinline__ float bf2f(ushort u){ union{uint i; float f;} v; v.i=((uint)u)<<16; return v.f; }
__device__ __forceinline__ ushort f2bf(float f){ __hip_bfloat16 h=__float2bfloat16(f); return *reinterpret_cast<ushort*>(&h); }

__device__ __forceinline__ f32x4 mfma16(bf16x8 a, bf16x8 b, f32x4 c){
    return __builtin_amdgcn_mfma_f32_16x16x32_bf16(a, b, c, 0, 0, 0);
}

// wave computes rows 0..63 of act (LDS, row-major stride AS) x cols [n0,n0+64) of WT (bf16 [N][K=256])
__device__ __forceinline__ void wave_gemm(const ushort* act, const ushort* __restrict__ WT,
                                          int n0, int lane, f32x4 acc[4][4])
{
    #pragma unroll
    for (int mi=0;mi<4;mi++)
        #pragma unroll
        for (int ni=0;ni<4;ni++) acc[mi][ni]=(f32x4){0.f,0.f,0.f,0.f};
    const int rA=lane&15, kg=(lane>>4)*8;
    #pragma unroll
    for (int kk=0;kk<8;kk++){
        const int ka=kk*32+kg;
        bf16x8 a[4], b[4];
        #pragma unroll
        for (int mi=0;mi<4;mi++) a[mi]=*(const bf16x8*)&act[(mi*16+rA)*AS+ka];
        #pragma unroll
        for (int ni=0;ni<4;ni++) b[ni]=*(const bf16x8*)&WT[(size_t)((n0+ni*16+rA)*HID+ka)];
        #pragma unroll
        for (int mi=0;mi<4;mi++)
            #pragma unroll
            for (int ni=0;ni<4;ni++)
                acc[mi][ni]=mfma16(a[mi], b[ni], acc[mi][ni]);
    }
}

// scatter C-layout accumulator into act LDS (scalar b16 writes), optional relu
__device__ __forceinline__ void store_c_to_act(ushort* act, const f32x4 acc[4][4],
                                               int colb, int hi, bool relu)
{
    #pragma unroll
    for (int mi=0;mi<4;mi++)
        #pragma unroll
        for (int ni=0;ni<4;ni++)
            #pragma unroll
            for (int r=0;r<4;r++){
                float v=acc[mi][ni][r];
                if (relu) v=fmaxf(v,0.f);
                act[(mi*16+hi*4+r)*AS + colb+ni*16]=f2bf(v);
            }
}

// ---------------- combined weights -> bf16 transposed (+K=32 layer1 weights with bias folded)
__global__ void combine_weights(const float* __restrict__ sW2, const float* __restrict__ sb2,
                                const float* __restrict__ eW2, const float* __restrict__ eb2,
                                const float* __restrict__ gW1, const float* __restrict__ gb1,
                                const float* __restrict__ dW2, const float* __restrict__ gW2,
                                const float* __restrict__ oW1,
                                const float* __restrict__ eW1, const float* __restrict__ eb1,
                                const float* __restrict__ sW1, const float* __restrict__ sb1,
                                const float* __restrict__ dW1, const float* __restrict__ db1,
                                const float* __restrict__ oW2,
                                ushort* __restrict__ WT_A, ushort* __restrict__ WT_B, ushort* __restrict__ WT_E,
                                ushort* __restrict__ WT_d, ushort* __restrict__ WT_g, ushort* __restrict__ WT_o,
                                ushort* __restrict__ WT_e1, ushort* __restrict__ WT_s1, ushort* __restrict__ WT_d1,
                                ushort* __restrict__ WT_o2p,
                                float* __restrict__ bias_A, float* __restrict__ bias_B)
{
    const int j = threadIdx.x;
    const int i = blockIdx.x;   // 0..256 (256 = bias row for m<3)
    const int m = blockIdx.y;   // 0:A 1:B 2:E 3:dW2 4:gW2 5:oW1 6:e1 7:s1 8:d1 9:o2p
    if (m==6){ if (i<32) WT_e1[j*32+i] = f2bf(i<3 ? eW1[i*HID+j] : (i==3 ? eb1[j] : 0.f)); return; }
    if (m==7){ if (i<32) WT_s1[j*32+i] = f2bf(i<10? sW1[i*HID+j] : (i==10? sb1[j] : 0.f)); return; }
    if (m==8){ if (i<32) WT_d1[j*32+i] = f2bf(i<12? dW1[i*HID+j] : (i==12? db1[j] : 0.f)); return; }
    if (m==9){ if (i<16) WT_o2p[i*HID+j] = f2bf(i<3 ? oW2[j*3+i] : 0.f); return; }  // [16 n][256 k]
    if (m>=3){
        if (i<HID){
            const float* S = (m==3)? dW2 : (m==4)? gW2 : oW1;
            ushort* D      = (m==3)? WT_d : (m==4)? WT_g : WT_o;
            D[j*HID+i]=f2bf(S[i*HID+j]);
        }
        return;
    }
    const float* L  = (m==2)? eW2 : sW2;
    const float* R  = gW1 + (m==0 ? HID*HID : (m==1 ? 2*HID*HID : 0));
    if (i < HID){
        float acc=0.f;
        for (int k=0;k<HID;k++) acc += L[i*HID+k]*R[k*HID+j];
        (m==0?WT_A:(m==1?WT_B:WT_E))[j*HID+i] = f2bf(acc);
    } else if (m==0){
        float acc=gb1[j];
        for (int k=0;k<HID;k++) acc += sb2[k]*gW1[(HID+k)*HID+j];
        for (int k=0;k<HID;k++) acc += eb2[k]*gW1[k*HID+j];
        bias_A[j]=acc;
    } else if (m==1){
        float acc=0.f;
        for (int k=0;k<HID;k++) acc += sb2[k]*gW1[(2*HID+k)*HID+j];
        bias_B[j]=acc;
    }
}

// ---------------- node encoder (all-MFMA): gA/gB (bf16) + h0 (bf16)
__global__ __launch_bounds__(256) void node_encode_mfma(
    const float* __restrict__ sfeat, const float* __restrict__ dfeat,
    const ushort* __restrict__ WT_s1, const ushort* __restrict__ WT_d1,
    const ushort* __restrict__ WT_d, const float* __restrict__ db2,
    const ushort* __restrict__ WT_A, const float* __restrict__ bias_A,
    const ushort* __restrict__ WT_B, const float* __restrict__ bias_B,
    ushort* __restrict__ gA, ushort* __restrict__ gB, ushort* __restrict__ h0)
{
    __shared__ ushort act[64*AS];
    __shared__ ushort A0[64*A0S];
    const int tid=threadIdx.x;
    const int n0blk=blockIdx.x*64;
    const int wv=tid>>6, lane=tid&63, n0=wv*64;
    const int rA=lane&15, kg=(lane>>4)*8, hi=lane>>4;
    const int colb=n0+rA;

    {   // stage A0 = [sfeat(10), 1, 0...]
        const int n=tid>>2, k0=(tid&3)*8;
        const int gn=n0blk+n;
        u16x8 v;
        #pragma unroll
        for (int j=0;j<8;j++){
            const int k=k0+j;
            float f = (gn<N_NODES && k<10)? sfeat[(size_t)gn*10+k] : (k==10? 1.f : 0.f);
            v[j]=f2bf(f);
        }
        *(u16x8*)&A0[n*A0S+k0]=v;
    }
    __syncthreads();
    f32x4 acc[4][4];
    {   // layer1 static: relu(A0 @ WT_s1^T)
        bf16x8 a[4], b[4];
        #pragma unroll
        for (int mi=0;mi<4;mi++) a[mi]=*(const bf16x8*)&A0[(mi*16+rA)*A0S+kg];
        #pragma unroll
        for (int ni=0;ni<4;ni++) b[ni]=*(const bf16x8*)&WT_s1[(size_t)(n0+ni*16+rA)*32+kg];
        #pragma unroll
        for (int mi=0;mi<4;mi++)
            #pragma unroll
            for (int ni=0;ni<4;ni++)
                acc[mi][ni]=mfma16(a[mi], b[ni], (f32x4){0.f,0.f,0.f,0.f});
        store_c_to_act(act, acc, colb, hi, true);
    }
    __syncthreads();
    {   // stage A0 dynamic (A0 free after gemm above)
        const int n=tid>>2, k0=(tid&3)*8;
        const int gn=n0blk+n;
        u16x8 v;
        #pragma unroll
        for (int j=0;j<8;j++){
            const int k=k0+j;
            float f = (gn<N_NODES && k<12)? dfeat[(size_t)gn*12+k] : (k==12? 1.f : 0.f);
            v[j]=f2bf(f);
        }
        *(u16x8*)&A0[n*A0S+k0]=v;
    }
    {   // gA = act @ WT_A^T + bias_A(total)
        wave_gemm(act, WT_A, n0, lane, acc);
        #pragma unroll
        for (int mi=0;mi<4;mi++){
            #pragma unroll
            for (int ni=0;ni<4;ni++){
                const int col=colb+ni*16; const float bA=bias_A[col];
                #pragma unroll
                for (int r=0;r<4;r++){
                    int rr=mi*16+hi*4+r; int gn=n0blk+rr;
                    if (gn<N_NODES) gA[(size_t)gn*HID+col]=f2bf(acc[mi][ni][r]+bA);
                }
            }
        }
    }
    {   // gB
        wave_gemm(act, WT_B, n0, lane, acc);
        #pragma unroll
        for (int mi=0;mi<4;mi++){
            #pragma unroll
            for (int ni=0;ni<4;ni++){
                const int col=colb+ni*16; const float bB=bias_B[col];
                #pragma unroll
                for (int r=0;r<4;r++){
                    int rr=mi*16+hi*4+r; int gn=n0blk+rr;
                    if (gn<N_NODES) gB[(size_t)gn*HID+col]=f2bf(acc[mi][ni][r]+bB);
                }
            }
        }
    }
    __syncthreads();   // all waves done reading act + A0d staged
    {   // layer1 dynamic: relu(A0 @ WT_d1^T)
        bf16x8 a[4], b[4];
        #pragma unroll
        for (int mi=0;mi<4;mi++) a[mi]=*(const bf16x8*)&A0[(mi*16+rA)*A0S+kg];
        #pragma unroll
        for (int ni=0;ni<4;ni++) b[ni]=*(const bf16x8*)&WT_d1[(size_t)(n0+ni*16+rA)*32+kg];
        #pragma unroll
        for (int mi=0;mi<4;mi++)
            #pragma unroll
            for (int ni=0;ni<4;ni++)
                acc[mi][ni]=mfma16(a[mi], b[ni], (f32x4){0.f,0.f,0.f,0.f});
        store_c_to_act(act, acc, colb, hi, true);
    }
    __syncthreads();
    {   // h0 = act @ WT_d^T + db2
        wave_gemm(act, WT_d, n0, lane, acc);
        #pragma unroll
        for (int mi=0;mi<4;mi++){
            #pragma unroll
            for (int ni=0;ni<4;ni++){
                const int col=colb+ni*16; const float bo=db2[col];
                #pragma unroll
                for (int r=0;r<4;r++){
                    int rr=mi*16+hi*4+r; int gn=n0blk+rr;
                    if (gn<N_NODES) h0[(size_t)gn*HID+col]=f2bf(acc[mi][ni][r]+bo);
                }
            }
        }
    }
}

// ---------------- edge encoder: 128-edge tile, 8 waves (2M x 4N), all-MFMA, CSR-slot order
// (exact round-8 structure — green; DO NOT TOUCH)
__global__ __launch_bounds__(512) void edge_encode_mfma(
    const float* __restrict__ eattr, const int* __restrict__ eidx,
    const int* __restrict__ csr_src, const int* __restrict__ csr_eid,
    const ushort* __restrict__ WT_e1,
    const ushort* __restrict__ WT_E,
    const ushort* __restrict__ WT_g2, const float* __restrict__ gb2,
    const ushort* __restrict__ gA, const ushort* __restrict__ gB,
    ushort* __restrict__ g_out)
{
    __shared__ ushort act[128*AS];    // 67.6 KB
    __shared__ ushort A0[128*A0S];    // 10.25 KB
    __shared__ int si[128], di[128], ei[128];
    const int tid=threadIdx.x;
    const int bid=blockIdx.x;
    const int s0=((bid&7)*293 + (bid>>3))*128;
    const int wv=tid>>6, lane=tid&63;
    const int wm=wv>>2, wn=wv&3;          // 2M x 4N wave grid
    const int m0=wm*64, n0=wn*64;
    const int rA=lane&15, kg=(lane>>4)*8, hi=lane>>4;
    const int colb=n0+rA;

    if (tid<128){
        int s=s0+tid; bool v=s<N_EDGES;
        int eid=v? csr_eid[s]:0;
        si[tid]=v? csr_src[s]:0;
        di[tid]=v? eidx[N_EDGES+eid]:0;
        ei[tid]=eid;
    }
    __syncthreads();
    {   // stage A0 = [eattr(3), 1, 0...]  (4 threads per row)
        const int n=tid>>2, k0=(tid&3)*8;
        const int eid=ei[n];
        u16x8 v;
        #pragma unroll
        for (int j=0;j<8;j++){
            const int k=k0+j;
            float f = (k<3)? eattr[(size_t)eid*3+k] : (k==3? 1.f : 0.f);
            v[j]=f2bf(f);
        }
        *(u16x8*)&A0[n*A0S+k0]=v;
    }
    __syncthreads();
    f32x4 acc[4][4];
    {   // gemm0: e1 = relu(A0 @ WT_e1^T), K=32, rows m0..m0+63
        bf16x8 a[4], b[4];
        #pragma unroll
        for (int mi=0;mi<4;mi++) a[mi]=*(const bf16x8*)&A0[(m0+mi*16+rA)*A0S+kg];
        #pragma unroll
        for (int ni=0;ni<4;ni++) b[ni]=*(const bf16x8*)&WT_e1[(size_t)(n0+ni*16+rA)*32+kg];
        #pragma unroll
        for (int mi=0;mi<4;mi++)
            #pragma unroll
            for (int ni=0;ni<4;ni++)
                acc[mi][ni]=mfma16(a[mi], b[ni], (f32x4){0.f,0.f,0.f,0.f});
        store_c_to_act(act + m0*AS, acc, colb, hi, true);
    }
    __syncthreads();
    wave_gemm(act + m0*AS, WT_E, n0, lane, acc);   // gemm1 on own 64-row group
    __syncthreads();                               // all waves done reading act
    store_c_to_act(act + m0*AS, acc, colb, hi, false);   // raw acc1 into own 64x64 patch
    {   // fused remap of own patch (intra-wave dep only)
        const int row=m0+lane;
        const ushort* garow=&gA[(size_t)si[row]*HID + n0];
        const ushort* gbrow=&gB[(size_t)di[row]*HID + n0];
        ushort* arow=&act[row*AS + n0];
        #pragma unroll
        for (int j=0;j<8;j++){
            const int jb=((j+lane)&7)*8;
            u16x8 av=*(u16x8*)&arow[jb];
            u16x8 ga=*(const u16x8*)&garow[jb];
            u16x8 gb=*(const u16x8*)&gbrow[jb];
            u16x8 o;
            #pragma unroll
            for (int q=0;q<8;q++)
                o[q]=f2bf(fmaxf(bf2f(av[q])+bf2f(ga[q])+bf2f(gb[q]),0.f));
            *(u16x8*)&arow[jb]=o;
        }
    }
    __syncthreads();
    wave_gemm(act + m0*AS, WT_g2, n0, lane, acc);  // gemm2
    {   // epilogue: + gb2 -> g_out[slot] (C-layout direct stores)
        #pragma unroll
        for (int mi=0;mi<4;mi++){
            #pragma unroll
            for (int ni=0;ni<4;ni++){
                const int col=colb+ni*16; const float bg=gb2[col];
                #pragma unroll
                for (int r=0;r<4;r++){
                    const int rr=m0+mi*16+hi*4+r;
                    if (s0+rr<N_EDGES)
                        g_out[(size_t)(s0+rr)*HID+col]=f2bf(acc[mi][ni][r]+bg);
                }
            }
        }
    }
}

// ---------------- CSR build
__global__ void deg_count(const int* __restrict__ eidx, uint* __restrict__ deg){
    int e=blockIdx.x*blockDim.x+threadIdx.x;
    if (e<N_EDGES) atomicAdd(&deg[eidx[N_EDGES+e]],1u);
}

// single-block prefix scan, 4 elements/thread/iteration (13 rounds)
__global__ void scan_kernel(const uint* __restrict__ deg, uint* __restrict__ row_start){
    __shared__ uint wtot[16];
    __shared__ uint woff[17];
    __shared__ uint carry_s;
    const int tid=threadIdx.x, lane=tid&63, wid=tid>>6;
    if (tid==0) carry_s=0;
    __syncthreads();
    for (uint base=0; base<N_NODES; base+=4096){
        uint idx=base+tid*4;
        uint v0=(idx  <N_NODES)? deg[idx  ]:0u;
        uint v1=(idx+1<N_NODES)? deg[idx+1]:0u;
        uint v2=(idx+2<N_NODES)? deg[idx+2]:0u;
        uint v3=(idx+3<N_NODES)? deg[idx+3]:0u;
        uint s4=v0+v1+v2+v3;
        uint s=s4;
        #pragma unroll
        for (int d=1; d<64; d<<=1){
            uint t=__shfl_up(s,d,64);
            if (lane>=d) s+=t;
        }
        if (lane==63) wtot[wid]=s;
        __syncthreads();
        if (tid==0){ uint r=0; for (int i=0;i<16;i++){ woff[i]=r; r+=wtot[i]; } woff[16]=r; }
        __syncthreads();
        uint excl = carry_s + woff[wid] + s - s4;
        if (idx  <N_NODES) row_start[idx  ]=excl;
        if (idx+1<N_NODES) row_start[idx+1]=excl+v0;
        if (idx+2<N_NODES) row_start[idx+2]=excl+v0+v1;
        if (idx+3<N_NODES) row_start[idx+3]=excl+v0+v1+v2;
        __syncthreads();
        if (tid==0) carry_s += woff[16];
        __syncthreads();
    }
}

__global__ void csr_fill(const int* __restrict__ eidx, const uint* __restrict__ row_start,
                         uint* __restrict__ cursor, int* __restrict__ csr_src, int* __restrict__ csr_eid){
    int e=blockIdx.x*blockDim.x+threadIdx.x;
    if (e>=N_EDGES) return;
    int d=eidx[N_EDGES+e];
    uint pos=atomicAdd(&cursor[d],1u);
    uint s=row_start[d]+pos;
    csr_src[s]=eidx[e];
    csr_eid[s]=e;
}

// ---------------- message-passing hop: one wave per node, CSR gather, bf16 h in/out
// 4x-unrolled neighbor loop (independent chains); TANH=true fuses the gnn activation on output
template<bool TANH>
__global__ __launch_bounds__(256) void hop_kernel(
    const ushort* __restrict__ h_in, ushort* __restrict__ h_out,
    const ushort* __restrict__ g, const int* __restrict__ csr_src,
    const uint* __restrict__ row_start, const uint* __restrict__ deg)
{
    const int gw=(blockIdx.x*blockDim.x+threadIdx.x)>>6;
    if (gw>=N_NODES) return;
    const int c0=(threadIdx.x&63)*4;
    ushort4 hd4=*(const ushort4*)&h_in[(size_t)gw*HID+c0];
    float4 hd; hd.x=bf2f(hd4.x); hd.y=bf2f(hd4.y); hd.z=bf2f(hd4.z); hd.w=bf2f(hd4.w);
    float4 a0=make_float4(0,0,0,0), a1=make_float4(0,0,0,0);
    float4 a2=make_float4(0,0,0,0), a3=make_float4(0,0,0,0);
    const uint st=row_start[gw], len=deg[gw];
    uint u=0;
    for (; u+4<=len; u+=4){
        int n0=csr_src[st+u], n1=csr_src[st+u+1], n2=csr_src[st+u+2], n3=csr_src[st+u+3];
        ushort4 g0=*(const ushort4*)&g[(size_t)(st+u  )*HID+c0];
        ushort4 g1=*(const ushort4*)&g[(size_t)(st+u+1)*HID+c0];
        ushort4 g2=*(const ushort4*)&g[(size_t)(st+u+2)*HID+c0];
        ushort4 g3=*(const ushort4*)&g[(size_t)(st+u+3)*HID+c0];
        ushort4 h0v=*(const ushort4*)&h_in[(size_t)n0*HID+c0];
        ushort4 h1v=*(const ushort4*)&h_in[(size_t)n1*HID+c0];
        ushort4 h2v=*(const ushort4*)&h_in[(size_t)n2*HID+c0];
        ushort4 h3v=*(const ushort4*)&h_in[(size_t)n3*HID+c0];
        a0.x+=bf2f(g0.x)*(bf2f(h0v.x)-hd.x); a0.y+=bf2f(g0.y)*(bf2f(h0v.y)-hd.y);
        a0.z+=bf2f(g0.z)*(bf2f(h0v.z)-hd.z); a0.w+=bf2f(g0.w)*(bf2f(h0v.w)-hd.w);
        a1.x+=bf2f(g1.x)*(bf2f(h1v.x)-hd.x); a1.y+=bf2f(g1.y)*(bf2f(h1v.y)-hd.y);
        a1.z+=bf2f(g1.z)*(bf2f(h1v.z)-hd.z); a1.w+=bf2f(g1.w)*(bf2f(h1v.w)-hd.w);
        a2.x+=bf2f(g2.x)*(bf2f(h2v.x)-hd.x); a2.y+=bf2f(g2.y)*(bf2f(h2v.y)-hd.y);
        a2.z+=bf2f(g2.z)*(bf2f(h2v.z)-hd.z); a2.w+=bf2f(g2.w)*(bf2f(h2v.w)-hd.w);
        a3.x+=bf2f(g3.x)*(bf2f(h3v.x)-hd.x); a3.y+=bf2f(g3.y)*(bf2f(h3v.y)-hd.y);
        a3.z+=bf2f(g3.z)*(bf2f(h3v.z)-hd.z); a3.w+=bf2f(g3.w)*(bf2f(h3v.w)-hd.w);
    }
    for (; u<len; u++){
        int n0=csr_src[st+u];
        ushort4 g0=*(const ushort4*)&g[(size_t)(st+u)*HID+c0];
        ushort4 h0v=*(const ushort4*)&h_in[(size_t)n0*HID+c0];
        a0.x+=bf2f(g0.x)*(bf2f(h0v.x)-hd.x); a0.y+=bf2f(g0.y)*(bf2f(h0v.y)-hd.y);
        a0.z+=bf2f(g0.z)*(bf2f(h0v.z)-hd.z); a0.w+=bf2f(g0.w)*(bf2f(h0v.w)-hd.w);
    }
    const float inv=1.f/fmaxf((float)len,1.f);
    float vx=hd.x+(a0.x+a1.x+a2.x+a3.x)*inv;
    float vy=hd.y+(a0.y+a1.y+a2.y+a3.y)*inv;
    float vz=hd.z+(a0.z+a1.z+a2.z+a3.z)*inv;
    float vw=hd.w+(a0.w+a1.w+a2.w+a3.w)*inv;
    if (TANH){ vx=tanhf(vx); vy=tanhf(vy); vz=tanhf(vz); vw=tanhf(vw); }
    ushort4 o; o.x=f2bf(vx); o.y=f2bf(vy); o.z=f2bf(vz); o.w=f2bf(vw);
    *(ushort4*)&h_out[(size_t)gw*HID+c0]=o;
}

// ---------------- decoder (all-MFMA): out = relu(x@oW1+ob1)@oW2+ob2   (x = tanh(h), pre-applied)
__global__ __launch_bounds__(256) void decoder_mfma(
    const ushort* __restrict__ x, const ushort* __restrict__ WT_o,
    const float* __restrict__ ob1, const ushort* __restrict__ WT_o2p, const float* __restrict__ ob2,
    float* __restrict__ out)
{
    __shared__ ushort act[64*AS];
    const int tid=threadIdx.x, n0blk=blockIdx.x*64;
    const int wv=tid>>6, lane=tid&63, n0=wv*64;
    const int rA=lane&15, kg=(lane>>4)*8, hi=lane>>4;
    const int colb=n0+rA;
    {   // stage x -> act (pure copy; tanh already applied)
        const int row=tid>>2, cc=(tid&3)*64;
        const int gn=n0blk+row;
        #pragma unroll
        for (int k=0;k<64;k+=8){
            u16x8 t;
            #pragma unroll
            for (int j=0;j<8;j++) t[j]=0;
            if (gn<N_NODES) t=*(const u16x8*)&x[(size_t)gn*HID+cc+k];
            *(u16x8*)&act[row*AS+cc+k]=t;
        }
    }
    __syncthreads();
    f32x4 acc[4][4];
    wave_gemm(act, WT_o, n0, lane, acc);
    __syncthreads();
    #pragma unroll
    for (int mi=0;mi<4;mi++){
        #pragma unroll
        for (int ni=0;ni<4;ni++){
            const int col=colb+ni*16; const float b1=ob1[col];
            #pragma unroll
            for (int r=0;r<4;r++){
                const int rr=mi*16+hi*4+r;
                act[rr*AS+col]=f2bf(fmaxf(acc[mi][ni][r]+b1,0.f));
            }
        }
    }
    __syncthreads();
    {   // final layer via MFMA, N padded 3->16: each wave does 16 rows (wv*16..+16)
        const int m0p=wv*16;
        f32x4 a2=(f32x4){0.f,0.f,0.f,0.f};
        #pragma unroll
        for (int kk=0;kk<8;kk++){
            const int ka=kk*32+kg;
            bf16x8 a=*(const bf16x8*)&act[(m0p+rA)*AS+ka];
            bf16x8 b=*(const bf16x8*)&WT_o2p[(size_t)rA*HID+ka];
            a2=mfma16(a, b, a2);
        }
        const int col=rA;        // n = lane&15 (0..15, valid cols 0..2)
        if (col<3){
            const float b2=ob2[col];
            #pragma unroll
            for (int r=0;r<4;r++){
                const int gn=n0blk+m0p+hi*4+r;
                if (gn<N_NODES) out[(size_t)gn*3+col]=a2[r]+b2;
            }
        }
    }
}

extern "C" void kernel_launch(void* const* d_in, const int* in_sizes, int n_in,
                              void* d_out, int out_size, void* d_ws, size_t ws_size,
                              hipStream_t stream)
{
    (void)in_sizes; (void)n_in; (void)out_size;
    const float* sfeat=(const float*)d_in[0];
    const float* dfeat=(const float*)d_in[1];
    const int*   eidx =(const int*)  d_in[2];
    const float* eattr=(const float*)d_in[3];
    const float* sW1=(const float*)d_in[4];  const float* sb1=(const float*)d_in[5];
    const float* sW2=(const float*)d_in[6];  const float* sb2=(const float*)d_in[7];
    const float* dW1=(const float*)d_in[8];  const float* db1=(const float*)d_in[9];
    const float* dW2=(const float*)d_in[10]; const float* db2=(const float*)d_in[11];
    const float* eW1=(const float*)d_in[12]; const float* eb1=(const float*)d_in[13];
    const float* eW2=(const float*)d_in[14]; const float* eb2=(const float*)d_in[15];
    const float* gW1=(const float*)d_in[16]; const float* gb1=(const float*)d_in[17];
    const float* gW2=(const float*)d_in[18]; const float* gb2=(const float*)d_in[19];
    const float* oW1=(const float*)d_in[20]; const float* ob1=(const float*)d_in[21];
    const float* oW2=(const float*)d_in[22]; const float* ob2=(const float*)d_in[23];
    float* out=(float*)d_out;

    char* p=(char*)d_ws;
    size_t used=0;
    auto alloc=[&](size_t bytes)->char*{
        char* r=p+used; used += (bytes+255)&~(size_t)255; return r;
    };
    ushort* WT_A=(ushort*)alloc(HID*HID*2);
    ushort* WT_B=(ushort*)alloc(HID*HID*2);
    ushort* WT_E=(ushort*)alloc(HID*HID*2);
    ushort* WT_d=(ushort*)alloc(HID*HID*2);
    ushort* WT_g=(ushort*)alloc(HID*HID*2);
    ushort* WT_o=(ushort*)alloc(HID*HID*2);
    ushort* WT_e1=(ushort*)alloc(HID*32*2);
    ushort* WT_s1=(ushort*)alloc(HID*32*2);
    ushort* WT_d1=(ushort*)alloc(HID*32*2);
    ushort* WT_o2p=(ushort*)alloc(16*HID*2);
    float* bias_A=(float*)alloc(HID*4);
    float* bias_B=(float*)alloc(HID*4);
    ushort* gA=(ushort*)alloc((size_t)N_NODES*HID*2);
    ushort* gB=(ushort*)alloc((size_t)N_NODES*HID*2);
    ushort* g =(ushort*)alloc((size_t)N_EDGES*HID*2);
    ushort* h0=(ushort*)alloc((size_t)N_NODES*HID*2);
    uint* deg      =(uint*)alloc(N_NODES*4);
    uint* row_start=(uint*)alloc(N_NODES*4);
    uint* cursor   =(uint*)alloc(N_NODES*4);
    int* csr_src=(int*)alloc(N_EDGES*4);
    int* csr_eid=(int*)alloc(N_EDGES*4);
    ushort* h1=gA;   // alias: gA/gB dead after edge_encode

    if (used > ws_size) return;  // clean fail if ws too small

    hipMemsetAsync(deg, 0, N_NODES*4, stream);
    hipMemsetAsync(cursor, 0, N_NODES*4, stream);

    combine_weights<<<dim3(HID+1,10),256,0,stream>>>(sW2,sb2,eW2,eb2,gW1,gb1,dW2,gW2,oW1,eW1,eb1,sW1,sb1,dW1,db1,oW2,
                                                     WT_A,WT_B,WT_E,WT_d,WT_g,WT_o,WT_e1,WT_s1,WT_d1,WT_o2p,bias_A,bias_B);
    node_encode_mfma<<<(N_NODES+63)/64,256,0,stream>>>(sfeat,dfeat,WT_s1,WT_d1,WT_d,db2,WT_A,bias_A,WT_B,bias_B,gA,gB,h0);
    deg_count<<<(N_EDGES+255)/256,256,0,stream>>>(eidx,deg);
    scan_kernel<<<1,1024,0,stream>>>(deg,row_start);
    csr_fill<<<(N_EDGES+255)/256,256,0,stream>>>(eidx,row_start,cursor,csr_src,csr_eid);
    edge_encode_mfma<<<(N_EDGES+127)/128,512,0,stream>>>(eattr,eidx,csr_src,csr_eid,WT_e1,WT_E,WT_g,gb2,gA,gB,g);
    hop_kernel<false><<<N_NODES/4,256,0,stream>>>(h0,h1,g,csr_src,row_start,deg);
    hop_kernel<true ><<<N_NODES/4,256,0,stream>>>(h1,h0,g,csr_src,row_start,deg);
    decoder_mfma<<<(N_NODES+63)/64,256,0,stream>>>(h0,WT_o,ob1,WT_o2p,ob2,out);
}

// Round 15
// 527.746 us; speedup vs baseline: 1.1923x; 1.0088x over previous
//
#include <hip/hip_runtime.h>
#include <hip/hip_bf16.h>

#define N_NODES 50000
#define N_EDGES 300000
#define HID 256
#define AS 264      // LDS act stride in bf16 elems: 264*2=528B = 33*16 -> 16B-aligned rows
#define A0S 40      // A0 stride (ushorts): 80B rows, 16B-aligned

typedef unsigned int uint;
typedef unsigned short ushort;
typedef short bf16x8 __attribute__((ext_vector_type(8)));
typedef unsigned short u16x8 __attribute__((ext_vector_type(8)));
typedef float f32x4 __attribute__((ext_vector_type(4)));

__device__ __forceinline__ float bf2f(ushort u){ union{uint i; float f;} v; v.i=((uint)u)<<16; return v.f; }
__device__ __forceinline__ ushort f2bf(float f){ __hip_bfloat16 h=__float2bfloat16(f); return *reinterpret_cast<ushort*>(&h); }

__device__ __forceinline__ f32x4 mfma16(bf16x8 a, bf16x8 b, f32x4 c){
    return __builtin_amdgcn_mfma_f32_16x16x32_bf16(a, b, c, 0, 0, 0);
}

// wave computes rows 0..63 of act (LDS, row-major stride AS) x cols [n0,n0+64) of WT (bf16 [N][K=256])
__device__ __forceinline__ void wave_gemm(const ushort* act, const ushort* __restrict__ WT,
                                          int n0, int lane, f32x4 acc[4][4])
{
    #pragma unroll
    for (int mi=0;mi<4;mi++)
        #pragma unroll
        for (int ni=0;ni<4;ni++) acc[mi][ni]=(f32x4){0.f,0.f,0.f,0.f};
    const int rA=lane&15, kg=(lane>>4)*8;
    #pragma unroll
    for (int kk=0;kk<8;kk++){
        const int ka=kk*32+kg;
        bf16x8 a[4], b[4];
        #pragma unroll
        for (int mi=0;mi<4;mi++) a[mi]=*(const bf16x8*)&act[(mi*16+rA)*AS+ka];
        #pragma unroll
        for (int ni=0;ni<4;ni++) b[ni]=*(const bf16x8*)&WT[(size_t)((n0+ni*16+rA)*HID+ka)];
        #pragma unroll
        for (int mi=0;mi<4;mi++)
            #pragma unroll
            for (int ni=0;ni<4;ni++)
                acc[mi][ni]=mfma16(a[mi], b[ni], acc[mi][ni]);
    }
}

// scatter C-layout accumulator into act LDS (scalar b16 writes), optional relu
__device__ __forceinline__ void store_c_to_act(ushort* act, const f32x4 acc[4][4],
                                               int colb, int hi, bool relu)
{
    #pragma unroll
    for (int mi=0;mi<4;mi++)
        #pragma unroll
        for (int ni=0;ni<4;ni++)
            #pragma unroll
            for (int r=0;r<4;r++){
                float v=acc[mi][ni][r];
                if (relu) v=fmaxf(v,0.f);
                act[(mi*16+hi*4+r)*AS + colb+ni*16]=f2bf(v);
            }
}

// ---------------- combined weights -> bf16 transposed (+K=32 layer1 weights with bias folded)
__global__ void combine_weights(const float* __restrict__ sW2, const float* __restrict__ sb2,
                                const float* __restrict__ eW2, const float* __restrict__ eb2,
                                const float* __restrict__ gW1, const float* __restrict__ gb1,
                                const float* __restrict__ dW2, const float* __restrict__ gW2,
                                const float* __restrict__ oW1,
                                const float* __restrict__ eW1, const float* __restrict__ eb1,
                                const float* __restrict__ sW1, const float* __restrict__ sb1,
                                const float* __restrict__ dW1, const float* __restrict__ db1,
                                const float* __restrict__ oW2,
                                ushort* __restrict__ WT_A, ushort* __restrict__ WT_B, ushort* __restrict__ WT_E,
                                ushort* __restrict__ WT_d, ushort* __restrict__ WT_g, ushort* __restrict__ WT_o,
                                ushort* __restrict__ WT_e1, ushort* __restrict__ WT_s1, ushort* __restrict__ WT_d1,
                                ushort* __restrict__ WT_o2p,
                                float* __restrict__ bias_A, float* __restrict__ bias_B)
{
    const int j = threadIdx.x;
    const int i = blockIdx.x;   // 0..256 (256 = bias row for m<3)
    const int m = blockIdx.y;   // 0:A 1:B 2:E 3:dW2 4:gW2 5:oW1 6:e1 7:s1 8:d1 9:o2p
    if (m==6){ if (i<32) WT_e1[j*32+i] = f2bf(i<3 ? eW1[i*HID+j] : (i==3 ? eb1[j] : 0.f)); return; }
    if (m==7){ if (i<32) WT_s1[j*32+i] = f2bf(i<10? sW1[i*HID+j] : (i==10? sb1[j] : 0.f)); return; }
    if (m==8){ if (i<32) WT_d1[j*32+i] = f2bf(i<12? dW1[i*HID+j] : (i==12? db1[j] : 0.f)); return; }
    if (m==9){ if (i<16) WT_o2p[i*HID+j] = f2bf(i<3 ? oW2[j*3+i] : 0.f); return; }  // [16 n][256 k]
    if (m>=3){
        if (i<HID){
            const float* S = (m==3)? dW2 : (m==4)? gW2 : oW1;
            ushort* D      = (m==3)? WT_d : (m==4)? WT_g : WT_o;
            D[j*HID+i]=f2bf(S[i*HID+j]);
        }
        return;
    }
    const float* L  = (m==2)? eW2 : sW2;
    const float* R  = gW1 + (m==0 ? HID*HID : (m==1 ? 2*HID*HID : 0));
    if (i < HID){
        float acc=0.f;
        for (int k=0;k<HID;k++) acc += L[i*HID+k]*R[k*HID+j];
        (m==0?WT_A:(m==1?WT_B:WT_E))[j*HID+i] = f2bf(acc);
    } else if (m==0){
        float acc=gb1[j];
        for (int k=0;k<HID;k++) acc += sb2[k]*gW1[(HID+k)*HID+j];
        for (int k=0;k<HID;k++) acc += eb2[k]*gW1[k*HID+j];
        bias_A[j]=acc;
    } else if (m==1){
        float acc=0.f;
        for (int k=0;k<HID;k++) acc += sb2[k]*gW1[(2*HID+k)*HID+j];
        bias_B[j]=acc;
    }
}

// ---------------- node encoder (all-MFMA): gA/gB (bf16) + h0 (bf16)
__global__ __launch_bounds__(256) void node_encode_mfma(
    const float* __restrict__ sfeat, const float* __restrict__ dfeat,
    const ushort* __restrict__ WT_s1, const ushort* __restrict__ WT_d1,
    const ushort* __restrict__ WT_d, const float* __restrict__ db2,
    const ushort* __restrict__ WT_A, const float* __restrict__ bias_A,
    const ushort* __restrict__ WT_B, const float* __restrict__ bias_B,
    ushort* __restrict__ gA, ushort* __restrict__ gB, ushort* __restrict__ h0)
{
    __shared__ ushort act[64*AS];
    __shared__ ushort A0[64*A0S];
    const int tid=threadIdx.x;
    const int n0blk=blockIdx.x*64;
    const int wv=tid>>6, lane=tid&63, n0=wv*64;
    const int rA=lane&15, kg=(lane>>4)*8, hi=lane>>4;
    const int colb=n0+rA;

    {   // stage A0 = [sfeat(10), 1, 0...]
        const int n=tid>>2, k0=(tid&3)*8;
        const int gn=n0blk+n;
        u16x8 v;
        #pragma unroll
        for (int j=0;j<8;j++){
            const int k=k0+j;
            float f = (gn<N_NODES && k<10)? sfeat[(size_t)gn*10+k] : (k==10? 1.f : 0.f);
            v[j]=f2bf(f);
        }
        *(u16x8*)&A0[n*A0S+k0]=v;
    }
    __syncthreads();
    f32x4 acc[4][4];
    {   // layer1 static: relu(A0 @ WT_s1^T)
        bf16x8 a[4], b[4];
        #pragma unroll
        for (int mi=0;mi<4;mi++) a[mi]=*(const bf16x8*)&A0[(mi*16+rA)*A0S+kg];
        #pragma unroll
        for (int ni=0;ni<4;ni++) b[ni]=*(const bf16x8*)&WT_s1[(size_t)(n0+ni*16+rA)*32+kg];
        #pragma unroll
        for (int mi=0;mi<4;mi++)
            #pragma unroll
            for (int ni=0;ni<4;ni++)
                acc[mi][ni]=mfma16(a[mi], b[ni], (f32x4){0.f,0.f,0.f,0.f});
        store_c_to_act(act, acc, colb, hi, true);
    }
    __syncthreads();
    {   // stage A0 dynamic (A0 free after gemm above)
        const int n=tid>>2, k0=(tid&3)*8;
        const int gn=n0blk+n;
        u16x8 v;
        #pragma unroll
        for (int j=0;j<8;j++){
            const int k=k0+j;
            float f = (gn<N_NODES && k<12)? dfeat[(size_t)gn*12+k] : (k==12? 1.f : 0.f);
            v[j]=f2bf(f);
        }
        *(u16x8*)&A0[n*A0S+k0]=v;
    }
    {   // gA = act @ WT_A^T + bias_A(total)
        wave_gemm(act, WT_A, n0, lane, acc);
        #pragma unroll
        for (int mi=0;mi<4;mi++){
            #pragma unroll
            for (int ni=0;ni<4;ni++){
                const int col=colb+ni*16; const float bA=bias_A[col];
                #pragma unroll
                for (int r=0;r<4;r++){
                    int rr=mi*16+hi*4+r; int gn=n0blk+rr;
                    if (gn<N_NODES) gA[(size_t)gn*HID+col]=f2bf(acc[mi][ni][r]+bA);
                }
            }
        }
    }
    {   // gB
        wave_gemm(act, WT_B, n0, lane, acc);
        #pragma unroll
        for (int mi=0;mi<4;mi++){
            #pragma unroll
            for (int ni=0;ni<4;ni++){
                const int col=colb+ni*16; const float bB=bias_B[col];
                #pragma unroll
                for (int r=0;r<4;r++){
                    int rr=mi*16+hi*4+r; int gn=n0blk+rr;
                    if (gn<N_NODES) gB[(size_t)gn*HID+col]=f2bf(acc[mi][ni][r]+bB);
                }
            }
        }
    }
    __syncthreads();   // all waves done reading act + A0d staged
    {   // layer1 dynamic: relu(A0 @ WT_d1^T)
        bf16x8 a[4], b[4];
        #pragma unroll
        for (int mi=0;mi<4;mi++) a[mi]=*(const bf16x8*)&A0[(mi*16+rA)*A0S+kg];
        #pragma unroll
        for (int ni=0;ni<4;ni++) b[ni]=*(const bf16x8*)&WT_d1[(size_t)(n0+ni*16+rA)*32+kg];
        #pragma unroll
        for (int mi=0;mi<4;mi++)
            #pragma unroll
            for (int ni=0;ni<4;ni++)
                acc[mi][ni]=mfma16(a[mi], b[ni], (f32x4){0.f,0.f,0.f,0.f});
        store_c_to_act(act, acc, colb, hi, true);
    }
    __syncthreads();
    {   // h0 = act @ WT_d^T + db2
        wave_gemm(act, WT_d, n0, lane, acc);
        #pragma unroll
        for (int mi=0;mi<4;mi++){
            #pragma unroll
            for (int ni=0;ni<4;ni++){
                const int col=colb+ni*16; const float bo=db2[col];
                #pragma unroll
                for (int r=0;r<4;r++){
                    int rr=mi*16+hi*4+r; int gn=n0blk+rr;
                    if (gn<N_NODES) h0[(size_t)gn*HID+col]=f2bf(acc[mi][ni][r]+bo);
                }
            }
        }
    }
}

// ---------------- edge encoder: 128-edge tile, 8 waves (2M x 4N), all-MFMA, CSR-slot order
// (exact round-8 structure — green; DO NOT TOUCH)
__global__ __launch_bounds__(512) void edge_encode_mfma(
    const float* __restrict__ eattr, const int* __restrict__ eidx,
    const int* __restrict__ csr_src, const int* __restrict__ csr_eid,
    const ushort* __restrict__ WT_e1,
    const ushort* __restrict__ WT_E,
    const ushort* __restrict__ WT_g2, const float* __restrict__ gb2,
    const ushort* __restrict__ gA, const ushort* __restrict__ gB,
    ushort* __restrict__ g_out)
{
    __shared__ ushort act[128*AS];    // 67.6 KB
    __shared__ ushort A0[128*A0S];    // 10.25 KB
    __shared__ int si[128], di[128], ei[128];
    const int tid=threadIdx.x;
    const int bid=blockIdx.x;
    const int s0=((bid&7)*293 + (bid>>3))*128;
    const int wv=tid>>6, lane=tid&63;
    const int wm=wv>>2, wn=wv&3;          // 2M x 4N wave grid
    const int m0=wm*64, n0=wn*64;
    const int rA=lane&15, kg=(lane>>4)*8, hi=lane>>4;
    const int colb=n0+rA;

    if (tid<128){
        int s=s0+tid; bool v=s<N_EDGES;
        int eid=v? csr_eid[s]:0;
        si[tid]=v? csr_src[s]:0;
        di[tid]=v? eidx[N_EDGES+eid]:0;
        ei[tid]=eid;
    }
    __syncthreads();
    {   // stage A0 = [eattr(3), 1, 0...]  (4 threads per row)
        const int n=tid>>2, k0=(tid&3)*8;
        const int eid=ei[n];
        u16x8 v;
        #pragma unroll
        for (int j=0;j<8;j++){
            const int k=k0+j;
            float f = (k<3)? eattr[(size_t)eid*3+k] : (k==3? 1.f : 0.f);
            v[j]=f2bf(f);
        }
        *(u16x8*)&A0[n*A0S+k0]=v;
    }
    __syncthreads();
    f32x4 acc[4][4];
    {   // gemm0: e1 = relu(A0 @ WT_e1^T), K=32, rows m0..m0+63
        bf16x8 a[4], b[4];
        #pragma unroll
        for (int mi=0;mi<4;mi++) a[mi]=*(const bf16x8*)&A0[(m0+mi*16+rA)*A0S+kg];
        #pragma unroll
        for (int ni=0;ni<4;ni++) b[ni]=*(const bf16x8*)&WT_e1[(size_t)(n0+ni*16+rA)*32+kg];
        #pragma unroll
        for (int mi=0;mi<4;mi++)
            #pragma unroll
            for (int ni=0;ni<4;ni++)
                acc[mi][ni]=mfma16(a[mi], b[ni], (f32x4){0.f,0.f,0.f,0.f});
        store_c_to_act(act + m0*AS, acc, colb, hi, true);
    }
    __syncthreads();
    wave_gemm(act + m0*AS, WT_E, n0, lane, acc);   // gemm1 on own 64-row group
    __syncthreads();                               // all waves done reading act
    store_c_to_act(act + m0*AS, acc, colb, hi, false);   // raw acc1 into own 64x64 patch
    {   // fused remap of own patch (intra-wave dep only)
        const int row=m0+lane;
        const ushort* garow=&gA[(size_t)si[row]*HID + n0];
        const ushort* gbrow=&gB[(size_t)di[row]*HID + n0];
        ushort* arow=&act[row*AS + n0];
        #pragma unroll
        for (int j=0;j<8;j++){
            const int jb=((j+lane)&7)*8;
            u16x8 av=*(u16x8*)&arow[jb];
            u16x8 ga=*(const u16x8*)&garow[jb];
            u16x8 gb=*(const u16x8*)&gbrow[jb];
            u16x8 o;
            #pragma unroll
            for (int q=0;q<8;q++)
                o[q]=f2bf(fmaxf(bf2f(av[q])+bf2f(ga[q])+bf2f(gb[q]),0.f));
            *(u16x8*)&arow[jb]=o;
        }
    }
    __syncthreads();
    wave_gemm(act + m0*AS, WT_g2, n0, lane, acc);  // gemm2
    {   // epilogue: + gb2 -> g_out[slot] (C-layout direct stores)
        #pragma unroll
        for (int mi=0;mi<4;mi++){
            #pragma unroll
            for (int ni=0;ni<4;ni++){
                const int col=colb+ni*16; const float bg=gb2[col];
                #pragma unroll
                for (int r=0;r<4;r++){
                    const int rr=m0+mi*16+hi*4+r;
                    if (s0+rr<N_EDGES)
                        g_out[(size_t)(s0+rr)*HID+col]=f2bf(acc[mi][ni][r]+bg);
                }
            }
        }
    }
}

// ---------------- CSR build
__global__ void deg_count(const int* __restrict__ eidx, uint* __restrict__ deg){
    int e=blockIdx.x*blockDim.x+threadIdx.x;
    if (e<N_EDGES) atomicAdd(&deg[eidx[N_EDGES+e]],1u);
}

// single-block prefix scan, 4 elements/thread/iteration (13 rounds)
__global__ void scan_kernel(const uint* __restrict__ deg, uint* __restrict__ row_start){
    __shared__ uint wtot[16];
    __shared__ uint woff[17];
    __shared__ uint carry_s;
    const int tid=threadIdx.x, lane=tid&63, wid=tid>>6;
    if (tid==0) carry_s=0;
    __syncthreads();
    for (uint base=0; base<N_NODES; base+=4096){
        uint idx=base+tid*4;
        uint v0=(idx  <N_NODES)? deg[idx  ]:0u;
        uint v1=(idx+1<N_NODES)? deg[idx+1]:0u;
        uint v2=(idx+2<N_NODES)? deg[idx+2]:0u;
        uint v3=(idx+3<N_NODES)? deg[idx+3]:0u;
        uint s4=v0+v1+v2+v3;
        uint s=s4;
        #pragma unroll
        for (int d=1; d<64; d<<=1){
            uint t=__shfl_up(s,d,64);
            if (lane>=d) s+=t;
        }
        if (lane==63) wtot[wid]=s;
        __syncthreads();
        if (tid==0){ uint r=0; for (int i=0;i<16;i++){ woff[i]=r; r+=wtot[i]; } woff[16]=r; }
        __syncthreads();
        uint excl = carry_s + woff[wid] + s - s4;
        if (idx  <N_NODES) row_start[idx  ]=excl;
        if (idx+1<N_NODES) row_start[idx+1]=excl+v0;
        if (idx+2<N_NODES) row_start[idx+2]=excl+v0+v1;
        if (idx+3<N_NODES) row_start[idx+3]=excl+v0+v1+v2;
        __syncthreads();
        if (tid==0) carry_s += woff[16];
        __syncthreads();
    }
}

__global__ void csr_fill(const int* __restrict__ eidx, const uint* __restrict__ row_start,
                         uint* __restrict__ cursor, int* __restrict__ csr_src, int* __restrict__ csr_eid){
    int e=blockIdx.x*blockDim.x+threadIdx.x;
    if (e>=N_EDGES) return;
    int d=eidx[N_EDGES+e];
    uint pos=atomicAdd(&cursor[d],1u);
    uint s=row_start[d]+pos;
    csr_src[s]=eidx[e];
    csr_eid[s]=e;
}

// ---------------- message-passing hop: one wave per node, CSR gather, bf16 h in/out
// neighbor ids preloaded by lanes + __shfl broadcast -> no serial index-load chain.
// 4x-unrolled body; TANH=true fuses the gnn activation on output.
template<bool TANH>
__global__ __launch_bounds__(256) void hop_kernel(
    const ushort* __restrict__ h_in, ushort* __restrict__ h_out,
    const ushort* __restrict__ g, const int* __restrict__ csr_src,
    const uint* __restrict__ row_start, const uint* __restrict__ deg)
{
    const int gw=(blockIdx.x*blockDim.x+threadIdx.x)>>6;
    if (gw>=N_NODES) return;
    const int lane=threadIdx.x&63;
    const int c0=lane*4;
    ushort4 hd4=*(const ushort4*)&h_in[(size_t)gw*HID+c0];
    float4 hd; hd.x=bf2f(hd4.x); hd.y=bf2f(hd4.y); hd.z=bf2f(hd4.z); hd.w=bf2f(hd4.w);
    float4 a0=make_float4(0,0,0,0), a1=make_float4(0,0,0,0);
    float4 a2=make_float4(0,0,0,0), a3=make_float4(0,0,0,0);
    const uint st=row_start[gw], len=deg[gw];
    // preload neighbor ids: one coalesced load per wave, then shfl-broadcast (kills the
    // csr_src -> h_in dependent-load chain; g rows are contiguous so those stream anyway)
    const uint lim = (len<64u)? len : 64u;
    int nbr = (lane < (int)lim) ? csr_src[st+lane] : 0;
    uint u=0;
    for (; u+4<=lim; u+=4){
        int n0=__shfl(nbr,(int)u), n1=__shfl(nbr,(int)(u+1));
        int n2=__shfl(nbr,(int)(u+2)), n3=__shfl(nbr,(int)(u+3));
        ushort4 g0=*(const ushort4*)&g[(size_t)(st+u  )*HID+c0];
        ushort4 g1=*(const ushort4*)&g[(size_t)(st+u+1)*HID+c0];
        ushort4 g2=*(const ushort4*)&g[(size_t)(st+u+2)*HID+c0];
        ushort4 g3=*(const ushort4*)&g[(size_t)(st+u+3)*HID+c0];
        ushort4 h0v=*(const ushort4*)&h_in[(size_t)n0*HID+c0];
        ushort4 h1v=*(const ushort4*)&h_in[(size_t)n1*HID+c0];
        ushort4 h2v=*(const ushort4*)&h_in[(size_t)n2*HID+c0];
        ushort4 h3v=*(const ushort4*)&h_in[(size_t)n3*HID+c0];
        a0.x+=bf2f(g0.x)*(bf2f(h0v.x)-hd.x); a0.y+=bf2f(g0.y)*(bf2f(h0v.y)-hd.y);
        a0.z+=bf2f(g0.z)*(bf2f(h0v.z)-hd.z); a0.w+=bf2f(g0.w)*(bf2f(h0v.w)-hd.w);
        a1.x+=bf2f(g1.x)*(bf2f(h1v.x)-hd.x); a1.y+=bf2f(g1.y)*(bf2f(h1v.y)-hd.y);
        a1.z+=bf2f(g1.z)*(bf2f(h1v.z)-hd.z); a1.w+=bf2f(g1.w)*(bf2f(h1v.w)-hd.w);
        a2.x+=bf2f(g2.x)*(bf2f(h2v.x)-hd.x); a2.y+=bf2f(g2.y)*(bf2f(h2v.y)-hd.y);
        a2.z+=bf2f(g2.z)*(bf2f(h2v.z)-hd.z); a2.w+=bf2f(g2.w)*(bf2f(h2v.w)-hd.w);
        a3.x+=bf2f(g3.x)*(bf2f(h3v.x)-hd.x); a3.y+=bf2f(g3.y)*(bf2f(h3v.y)-hd.y);
        a3.z+=bf2f(g3.z)*(bf2f(h3v.z)-hd.z); a3.w+=bf2f(g3.w)*(bf2f(h3v.w)-hd.w);
    }
    for (; u<lim; u++){
        int n0=__shfl(nbr,(int)u);
        ushort4 g0=*(const ushort4*)&g[(size_t)(st+u)*HID+c0];
        ushort4 h0v=*(const ushort4*)&h_in[(size_t)n0*HID+c0];
        a0.x+=bf2f(g0.x)*(bf2f(h0v.x)-hd.x); a0.y+=bf2f(g0.y)*(bf2f(h0v.y)-hd.y);
        a0.z+=bf2f(g0.z)*(bf2f(h0v.z)-hd.z); a0.w+=bf2f(g0.w)*(bf2f(h0v.w)-hd.w);
    }
    for (; u<len; u++){   // rare tail (deg>64)
        int n0=csr_src[st+u];
        ushort4 g0=*(const ushort4*)&g[(size_t)(st+u)*HID+c0];
        ushort4 h0v=*(const ushort4*)&h_in[(size_t)n0*HID+c0];
        a0.x+=bf2f(g0.x)*(bf2f(h0v.x)-hd.x); a0.y+=bf2f(g0.y)*(bf2f(h0v.y)-hd.y);
        a0.z+=bf2f(g0.z)*(bf2f(h0v.z)-hd.z); a0.w+=bf2f(g0.w)*(bf2f(h0v.w)-hd.w);
    }
    const float inv=1.f/fmaxf((float)len,1.f);
    float vx=hd.x+(a0.x+a1.x+a2.x+a3.x)*inv;
    float vy=hd.y+(a0.y+a1.y+a2.y+a3.y)*inv;
    float vz=hd.z+(a0.z+a1.z+a2.z+a3.z)*inv;
    float vw=hd.w+(a0.w+a1.w+a2.w+a3.w)*inv;
    if (TANH){ vx=tanhf(vx); vy=tanhf(vy); vz=tanhf(vz); vw=tanhf(vw); }
    ushort4 o; o.x=f2bf(vx); o.y=f2bf(vy); o.z=f2bf(vz); o.w=f2bf(vw);
    *(ushort4*)&h_out[(size_t)gw*HID+c0]=o;
}

// ---------------- decoder (all-MFMA): out = relu(x@oW1+ob1)@oW2+ob2   (x = tanh(h), pre-applied)
__global__ __launch_bounds__(256) void decoder_mfma(
    const ushort* __restrict__ x, const ushort* __restrict__ WT_o,
    const float* __restrict__ ob1, const ushort* __restrict__ WT_o2p, const float* __restrict__ ob2,
    float* __restrict__ out)
{
    __shared__ ushort act[64*AS];
    const int tid=threadIdx.x, n0blk=blockIdx.x*64;
    const int wv=tid>>6, lane=tid&63, n0=wv*64;
    const int rA=lane&15, kg=(lane>>4)*8, hi=lane>>4;
    const int colb=n0+rA;
    {   // stage x -> act (pure copy; tanh already applied)
        const int row=tid>>2, cc=(tid&3)*64;
        const int gn=n0blk+row;
        #pragma unroll
        for (int k=0;k<64;k+=8){
            u16x8 t;
            #pragma unroll
            for (int j=0;j<8;j++) t[j]=0;
            if (gn<N_NODES) t=*(const u16x8*)&x[(size_t)gn*HID+cc+k];
            *(u16x8*)&act[row*AS+cc+k]=t;
        }
    }
    __syncthreads();
    f32x4 acc[4][4];
    wave_gemm(act, WT_o, n0, lane, acc);
    __syncthreads();
    #pragma unroll
    for (int mi=0;mi<4;mi++){
        #pragma unroll
        for (int ni=0;ni<4;ni++){
            const int col=colb+ni*16; const float b1=ob1[col];
            #pragma unroll
            for (int r=0;r<4;r++){
                const int rr=mi*16+hi*4+r;
                act[rr*AS+col]=f2bf(fmaxf(acc[mi][ni][r]+b1,0.f));
            }
        }
    }
    __syncthreads();
    {   // final layer via MFMA, N padded 3->16: each wave does 16 rows (wv*16..+16)
        const int m0p=wv*16;
        f32x4 a2=(f32x4){0.f,0.f,0.f,0.f};
        #pragma unroll
        for (int kk=0;kk<8;kk++){
            const int ka=kk*32+kg;
            bf16x8 a=*(const bf16x8*)&act[(m0p+rA)*AS+ka];
            bf16x8 b=*(const bf16x8*)&WT_o2p[(size_t)rA*HID+ka];
            a2=mfma16(a, b, a2);
        }
        const int col=rA;        // n = lane&15 (0..15, valid cols 0..2)
        if (col<3){
            const float b2=ob2[col];
            #pragma unroll
            for (int r=0;r<4;r++){
                const int gn=n0blk+m0p+hi*4+r;
                if (gn<N_NODES) out[(size_t)gn*3+col]=a2[r]+b2;
            }
        }
    }
}

extern "C" void kernel_launch(void* const* d_in, const int* in_sizes, int n_in,
                              void* d_out, int out_size, void* d_ws, size_t ws_size,
                              hipStream_t stream)
{
    (void)in_sizes; (void)n_in; (void)out_size;
    const float* sfeat=(const float*)d_in[0];
    const float* dfeat=(const float*)d_in[1];
    const int*   eidx =(const int*)  d_in[2];
    const float* eattr=(const float*)d_in[3];
    const float* sW1=(const float*)d_in[4];  const float* sb1=(const float*)d_in[5];
    const float* sW2=(const float*)d_in[6];  const float* sb2=(const float*)d_in[7];
    const float* dW1=(const float*)d_in[8];  const float* db1=(const float*)d_in[9];
    const float* dW2=(const float*)d_in[10]; const float* db2=(const float*)d_in[11];
    const float* eW1=(const float*)d_in[12]; const float* eb1=(const float*)d_in[13];
    const float* eW2=(const float*)d_in[14]; const float* eb2=(const float*)d_in[15];
    const float* gW1=(const float*)d_in[16]; const float* gb1=(const float*)d_in[17];
    const float* gW2=(const float*)d_in[18]; const float* gb2=(const float*)d_in[19];
    const float* oW1=(const float*)d_in[20]; const float* ob1=(const float*)d_in[21];
    const float* oW2=(const float*)d_in[22]; const float* ob2=(const float*)d_in[23];
    float* out=(float*)d_out;

    char* p=(char*)d_ws;
    size_t used=0;
    auto alloc=[&](size_t bytes)->char*{
        char* r=p+used; used += (bytes+255)&~(size_t)255; return r;
    };
    ushort* WT_A=(ushort*)alloc(HID*HID*2);
    ushort* WT_B=(ushort*)alloc(HID*HID*2);
    ushort* WT_E=(ushort*)alloc(HID*HID*2);
    ushort* WT_d=(ushort*)alloc(HID*HID*2);
    ushort* WT_g=(ushort*)alloc(HID*HID*2);
    ushort* WT_o=(ushort*)alloc(HID*HID*2);
    ushort* WT_e1=(ushort*)alloc(HID*32*2);
    ushort* WT_s1=(ushort*)alloc(HID*32*2);
    ushort* WT_d1=(ushort*)alloc(HID*32*2);
    ushort* WT_o2p=(ushort*)alloc(16*HID*2);
    float* bias_A=(float*)alloc(HID*4);
    float* bias_B=(float*)alloc(HID*4);
    ushort* gA=(ushort*)alloc((size_t)N_NODES*HID*2);
    ushort* gB=(ushort*)alloc((size_t)N_NODES*HID*2);
    ushort* g =(ushort*)alloc((size_t)N_EDGES*HID*2);
    ushort* h0=(ushort*)alloc((size_t)N_NODES*HID*2);
    uint* deg      =(uint*)alloc(N_NODES*4);
    uint* cursor   =(uint*)alloc(N_NODES*4);   // adjacent to deg -> single memset
    uint* row_start=(uint*)alloc(N_NODES*4);
    int* csr_src=(int*)alloc(N_EDGES*4);
    int* csr_eid=(int*)alloc(N_EDGES*4);
    ushort* h1=gA;   // alias: gA/gB dead after edge_encode

    if (used > ws_size) return;  // clean fail if ws too small

    hipMemsetAsync(deg, 0, (size_t)((char*)cursor - (char*)deg) + N_NODES*4, stream);

    combine_weights<<<dim3(HID+1,10),256,0,stream>>>(sW2,sb2,eW2,eb2,gW1,gb1,dW2,gW2,oW1,eW1,eb1,sW1,sb1,dW1,db1,oW2,
                                                     WT_A,WT_B,WT_E,WT_d,WT_g,WT_o,WT_e1,WT_s1,WT_d1,WT_o2p,bias_A,bias_B);
    node_encode_mfma<<<(N_NODES+63)/64,256,0,stream>>>(sfeat,dfeat,WT_s1,WT_d1,WT_d,db2,WT_A,bias_A,WT_B,bias_B,gA,gB,h0);
    deg_count<<<(N_EDGES+255)/256,256,0,stream>>>(eidx,deg);
    scan_kernel<<<1,1024,0,stream>>>(deg,row_start);
    csr_fill<<<(N_EDGES+255)/256,256,0,stream>>>(eidx,row_start,cursor,csr_src,csr_eid);
    edge_encode_mfma<<<(N_EDGES+127)/128,512,0,stream>>>(eattr,eidx,csr_src,csr_eid,WT_e1,WT_E,WT_g,gb2,gA,gB,g);
    hop_kernel<false><<<N_NODES/4,256,0,stream>>>(h0,h1,g,csr_src,row_start,deg);
    hop_kernel<true ><<<N_NODES/4,256,0,stream>>>(h1,h0,g,csr_src,row_start,deg);
    decoder_mfma<<<(N_NODES+63)/64,256,0,stream>>>(h0,WT_o,ob1,WT_o2p,ob2,out);
}